// Round 2
// baseline (14273.221 us; speedup 1.0000x reference)
//
#include <hip/hip_runtime.h>
#include <hip/hip_fp16.h>

#define BB 8
#define C 256
#define HH 56
#define WW 56
#define NN 3136      // HH*WW
#define RR 16
#define NT (NN/16)   // 196 pixel-tiles per image

// ---------------------------------------------------------------------------
// helpers
// ---------------------------------------------------------------------------
__device__ inline void load16h_to_f32(float* dst, const __half* src) {
  // src is 32B-aligned (offsets are multiples of 16 halves)
  const __half2* s2 = (const __half2*)src;
#pragma unroll
  for (int k = 0; k < 8; ++k) {
    float2 f = __half22float2(s2[k]);
    dst[2 * k] = f.x;
    dst[2 * k + 1] = f.y;
  }
}

// ---------------------------------------------------------------------------
// 1. attr branch fused: a = adj( concat( relu(W2 relu(W1 x)), x ) )
//    per block: 16 pixels of one image, all phases through LDS.
// ---------------------------------------------------------------------------
__global__ __launch_bounds__(256) void attr_kernel(
    const float* __restrict__ x,
    const float* __restrict__ w1, const float* __restrict__ b1,
    const float* __restrict__ w2, const float* __restrict__ b2,
    const float* __restrict__ wadj, const float* __restrict__ badj,
    float* __restrict__ a_out)
{
  __shared__ float xs[C][20];     // rows padded to 20 floats (16B-aligned rows)
  __shared__ float a2s[C][20];
  __shared__ float a1s[RR][20];
  const int tile = blockIdx.x;
  const int b = tile / NT;
  const int p0 = (tile % NT) * 16;
  const int t = threadIdx.x;

  // fill x tile: thread t = channel, 16 consecutive pixels (float4 x4)
  {
    const float* xb = x + ((size_t)b * C + t) * NN + p0;
    const float4* xb4 = (const float4*)xb;
    float* row = xs[t];
#pragma unroll
    for (int g = 0; g < 4; ++g) {
      float4 v = xb4[g];
      row[g * 4 + 0] = v.x; row[g * 4 + 1] = v.y;
      row[g * 4 + 2] = v.z; row[g * 4 + 3] = v.w;
    }
  }
  __syncthreads();

  // phase 1: a1[r][p] = relu(b1[r] + sum_c w1[r,c] * x[c][p])   (16x16 outputs)
  {
    const int r = t & 15, pp = t >> 4;
    float acc = b1[r];
    const float* wr = w1 + r * C;
    for (int c = 0; c < C; ++c) acc += wr[c] * xs[c][pp];
    a1s[r][pp] = fmaxf(acc, 0.f);
  }
  __syncthreads();

  // phase 2: a2[o][p] = relu(b2[o] + sum_k w2[o,k] * a1[k][p])
  {
    const int o = t;
    float acc[16];
    const float bias = b2[o];
#pragma unroll
    for (int p = 0; p < 16; ++p) acc[p] = bias;
    const float* wr = w2 + o * RR;
    for (int k = 0; k < RR; ++k) {
      const float w = wr[k];
#pragma unroll
      for (int p = 0; p < 16; ++p) acc[p] += w * a1s[k][p];
    }
    float* row = a2s[o];
#pragma unroll
    for (int p = 0; p < 16; ++p) row[p] = fmaxf(acc[p], 0.f);
  }
  __syncthreads();

  // phase 3: a[o][p] = badj[o] + sum_k wadj[o,k]*a2[k][p] + sum_k wadj[o,256+k]*x[k][p]
  {
    const int o = t;
    float acc[16];
    const float bias = badj[o];
#pragma unroll
    for (int p = 0; p < 16; ++p) acc[p] = bias;
    const float* wr = wadj + (size_t)o * (2 * C);
    for (int k = 0; k < C; ++k) {
      const float w = wr[k];
      const float4* ar = (const float4*)a2s[k];
#pragma unroll
      for (int g = 0; g < 4; ++g) {
        float4 v = ar[g];
        acc[g * 4 + 0] += w * v.x; acc[g * 4 + 1] += w * v.y;
        acc[g * 4 + 2] += w * v.z; acc[g * 4 + 3] += w * v.w;
      }
    }
    for (int k = 0; k < C; ++k) {
      const float w = wr[C + k];
      const float4* xr = (const float4*)xs[k];
#pragma unroll
      for (int g = 0; g < 4; ++g) {
        float4 v = xr[g];
        acc[g * 4 + 0] += w * v.x; acc[g * 4 + 1] += w * v.y;
        acc[g * 4 + 2] += w * v.z; acc[g * 4 + 3] += w * v.w;
      }
    }
    float* op = a_out + ((size_t)b * C + o) * NN + p0;
    float4* op4 = (float4*)op;
#pragma unroll
    for (int g = 0; g < 4; ++g)
      op4[g] = make_float4(acc[g * 4 + 0], acc[g * 4 + 1], acc[g * 4 + 2], acc[g * 4 + 3]);
  }
}

// ---------------------------------------------------------------------------
// 2. conv3x3 (pad 1).
//    flip=0: y[o] = sum_c W[o][c][ky][kx] * in[c][h+ky-1][w+kx-1]   (OIHW corr)
//    flip=1: y[o] = sum_c W[o][c][2-ky][2-kx] * in[c][h+ky-1][w+kx-1]
//      (JAX conv_transpose(IOHW, transpose_kernel=True) == spatial flip ONLY:
//       the flip+swapaxes composed with the IOHW spec reads channels as stored.)
//    Optional relu, optional *mul epilogue.
//    Block: one (b, h, 14-wide w-tile), thread = out channel.
// ---------------------------------------------------------------------------
__global__ __launch_bounds__(256) void conv3x3_kernel(
    const float* __restrict__ in, const float* __restrict__ w,
    const float* __restrict__ bias, const float* __restrict__ mul,
    float* __restrict__ out, int flip, int do_relu)
{
  __shared__ float ins[C][3][16];   // 3 rows x 16 cols (14 px + 2 halo)
  const int bid = blockIdx.x;
  const int b = bid / (HH * 4);
  const int rem = bid % (HH * 4);
  const int h = rem >> 2;
  const int w0 = (rem & 3) * 14;
  const int t = threadIdx.x;

  // fill: thread t = input channel
  {
    const float* ib = in + ((size_t)b * C + t) * NN;
#pragma unroll
    for (int dy = 0; dy < 3; ++dy) {
      const int gh = h + dy - 1;
      const bool rowok = (gh >= 0 && gh < HH);
#pragma unroll
      for (int j = 0; j < 16; ++j) {
        const int gw = w0 - 1 + j;
        float v = 0.f;
        if (rowok && gw >= 0 && gw < WW) v = ib[gh * WW + gw];
        ins[t][dy][j] = v;
      }
    }
  }
  __syncthreads();

  const int o = t;
  float acc[14];
#pragma unroll
  for (int p = 0; p < 14; ++p) acc[p] = 0.f;

  for (int c = 0; c < C; ++c) {
    const float* wp = w + ((size_t)o * C + c) * 9;   // channels as stored, both modes
#pragma unroll
    for (int dy = 0; dy < 3; ++dy) {
      float r[16];
      const float* rr = ins[c][dy];
#pragma unroll
      for (int j = 0; j < 16; ++j) r[j] = rr[j];
      float wA, wB, wC_;
      if (!flip) {
        wA = wp[dy * 3 + 0]; wB = wp[dy * 3 + 1]; wC_ = wp[dy * 3 + 2];
      } else {
        // tap (ky=dy, kx) uses W[o][c][2-dy][2-kx]
        wA = wp[(2 - dy) * 3 + 2]; wB = wp[(2 - dy) * 3 + 1]; wC_ = wp[(2 - dy) * 3 + 0];
      }
#pragma unroll
      for (int p = 0; p < 14; ++p)
        acc[p] += wA * r[p] + wB * r[p + 1] + wC_ * r[p + 2];
    }
  }

  const float bo = bias[o];
  const int pbase = h * WW + w0;
  float* op = out + ((size_t)b * C + o) * NN + pbase;
  if (mul != nullptr) {
    const float* mp = mul + ((size_t)b * C + o) * NN + pbase;
#pragma unroll
    for (int p = 0; p < 14; ++p) op[p] = (acc[p] + bo) * mp[p];
  } else if (do_relu) {
#pragma unroll
    for (int p = 0; p < 14; ++p) op[p] = fmaxf(acc[p] + bo, 0.f);
  } else {
#pragma unroll
    for (int p = 0; p < 14; ++p) op[p] = acc[p] + bo;
  }
}

// ---------------------------------------------------------------------------
// 3. fused Q/K/V linears: src [B][C][N] (channel-major) -> Q,K,V fp16 [B][N][C]
//    V is pre-scaled by vscale (folds ALPHA=0.5).
// ---------------------------------------------------------------------------
__global__ __launch_bounds__(256) void qkv_kernel(
    const float* __restrict__ src,
    const float* __restrict__ wq, const float* __restrict__ bq,
    const float* __restrict__ wk, const float* __restrict__ bk,
    const float* __restrict__ wv, const float* __restrict__ bv,
    __half* __restrict__ Q, __half* __restrict__ K, __half* __restrict__ V,
    float vscale)
{
  __shared__ float ss[C][20];
  const int tile = blockIdx.x;
  const int b = tile / NT;
  const int p0 = (tile % NT) * 16;
  const int t = threadIdx.x;
  {
    const float4* sb = (const float4*)(src + ((size_t)b * C + t) * NN + p0);
    float* row = ss[t];
#pragma unroll
    for (int g = 0; g < 4; ++g) {
      float4 v = sb[g];
      row[g * 4 + 0] = v.x; row[g * 4 + 1] = v.y;
      row[g * 4 + 2] = v.z; row[g * 4 + 3] = v.w;
    }
  }
  __syncthreads();

  const int o = t;
  float aq[16], ak[16], av[16];
  {
    const float q0 = bq[o], k0 = bk[o], v0 = bv[o];
#pragma unroll
    for (int p = 0; p < 16; ++p) { aq[p] = q0; ak[p] = k0; av[p] = v0; }
  }
  const float* wqr = wq + o * C;
  const float* wkr = wk + o * C;
  const float* wvr = wv + o * C;
  for (int k = 0; k < C; ++k) {
    const float fq = wqr[k], fk = wkr[k], fv = wvr[k];
    const float4* sr = (const float4*)ss[k];
#pragma unroll
    for (int g = 0; g < 4; ++g) {
      float4 s = sr[g];
      aq[g * 4 + 0] += fq * s.x; aq[g * 4 + 1] += fq * s.y; aq[g * 4 + 2] += fq * s.z; aq[g * 4 + 3] += fq * s.w;
      ak[g * 4 + 0] += fk * s.x; ak[g * 4 + 1] += fk * s.y; ak[g * 4 + 2] += fk * s.z; ak[g * 4 + 3] += fk * s.w;
      av[g * 4 + 0] += fv * s.x; av[g * 4 + 1] += fv * s.y; av[g * 4 + 2] += fv * s.z; av[g * 4 + 3] += fv * s.w;
    }
  }
#pragma unroll
  for (int p = 0; p < 16; ++p) {
    const size_t base = ((size_t)(b * NN) + p0 + p) * C + o;
    Q[base] = __float2half(aq[p]);
    K[base] = __float2half(ak[p]);
    V[base] = __float2half(av[p] * vscale);
  }
}

// ---------------------------------------------------------------------------
// 4. flash attention, 16 q-rows per block, 16-key tiles, online softmax.
//    O accumulated in registers; accumulate=1 adds into O (second attention).
// ---------------------------------------------------------------------------
__global__ __launch_bounds__(256) void flash_kernel(
    const __half* __restrict__ Q, const __half* __restrict__ K,
    const __half* __restrict__ V, float* __restrict__ O, int accumulate)
{
  __shared__ float Qs[16][260];
  __shared__ float Ks[16][260];
  __shared__ float Vs[16][260];
  __shared__ float Ps[16][20];
  __shared__ float ms[16], ls[16], fs[16];

  const int bid = blockIdx.x;
  const int b = bid / NT;
  const int q0 = (bid % NT) * 16;
  const int t = threadIdx.x;
  const int i = t >> 4;    // row within tile
  const int j = t & 15;    // col / 16-wide channel group

  load16h_to_f32(Qs[i] + j * 16, Q + ((size_t)(b * NN) + q0 + i) * C + j * 16);
  if (t < 16) { ms[t] = -1e30f; ls[t] = 0.f; }

  float oacc[16];
#pragma unroll
  for (int k = 0; k < 16; ++k) oacc[k] = 0.f;

  for (int kb = 0; kb < NT; ++kb) {
    __syncthreads();
    const size_t kbase = ((size_t)(b * NN) + kb * 16 + i) * C + j * 16;
    load16h_to_f32(Ks[i] + j * 16, K + kbase);
    load16h_to_f32(Vs[i] + j * 16, V + kbase);
    __syncthreads();

    // S[i][j] = scale * dot(Q row i, K row j)
    float s = 0.f;
    const float4* qr = (const float4*)Qs[i];
    const float4* kr = (const float4*)Ks[j];
#pragma unroll 8
    for (int c4 = 0; c4 < 64; ++c4) {
      float4 q = qr[c4], kk = kr[c4];
      s = fmaf(q.x, kk.x, s); s = fmaf(q.y, kk.y, s);
      s = fmaf(q.z, kk.z, s); s = fmaf(q.w, kk.w, s);
    }
    s *= 0.0625f;

    float mx = s;
    mx = fmaxf(mx, __shfl_xor(mx, 8));
    mx = fmaxf(mx, __shfl_xor(mx, 4));
    mx = fmaxf(mx, __shfl_xor(mx, 2));
    mx = fmaxf(mx, __shfl_xor(mx, 1));
    const float m_old = ms[i];
    const float m_new = fmaxf(m_old, mx);
    const float p = __expf(s - m_new);
    float rs = p;
    rs += __shfl_xor(rs, 8);
    rs += __shfl_xor(rs, 4);
    rs += __shfl_xor(rs, 2);
    rs += __shfl_xor(rs, 1);
    Ps[i][j] = p;
    if (j == 0) {
      const float f = __expf(m_old - m_new);
      fs[i] = f;
      ms[i] = m_new;
      ls[i] = ls[i] * f + rs;
    }
    __syncthreads();

    // O[i][16 channels] update; thread = (row i, channel group j)
    const float f = fs[i];
#pragma unroll
    for (int k = 0; k < 16; ++k) oacc[k] *= f;
#pragma unroll
    for (int jj = 0; jj < 16; ++jj) {
      const float pv = Ps[i][jj];
      const float4* vr = (const float4*)(Vs[jj] + j * 16);
#pragma unroll
      for (int g = 0; g < 4; ++g) {
        float4 v = vr[g];
        oacc[g * 4 + 0] = fmaf(pv, v.x, oacc[g * 4 + 0]);
        oacc[g * 4 + 1] = fmaf(pv, v.y, oacc[g * 4 + 1]);
        oacc[g * 4 + 2] = fmaf(pv, v.z, oacc[g * 4 + 2]);
        oacc[g * 4 + 3] = fmaf(pv, v.w, oacc[g * 4 + 3]);
      }
    }
  }

  const float inv = 1.f / ls[i];
  float4* op4 = (float4*)(O + ((size_t)(b * NN) + q0 + i) * C + j * 16);
  if (accumulate) {
#pragma unroll
    for (int g = 0; g < 4; ++g) {
      float4 prev = op4[g];
      prev.x += oacc[g * 4 + 0] * inv; prev.y += oacc[g * 4 + 1] * inv;
      prev.z += oacc[g * 4 + 2] * inv; prev.w += oacc[g * 4 + 3] * inv;
      op4[g] = prev;
    }
  } else {
#pragma unroll
    for (int g = 0; g < 4; ++g)
      op4[g] = make_float4(oacc[g * 4 + 0] * inv, oacc[g * 4 + 1] * inv,
                           oacc[g * 4 + 2] * inv, oacc[g * 4 + 3] * inv);
  }
}

// ---------------------------------------------------------------------------
// 5. out 1x1 conv + residual: o[b][c][p] = ob[c] + sum_k ow[c,k]*oattn[b][p][k] + x[b][c][p]
// ---------------------------------------------------------------------------
__global__ __launch_bounds__(256) void outconv_kernel(
    const float* __restrict__ oattn, const float* __restrict__ ow,
    const float* __restrict__ ob, const float* __restrict__ x,
    float* __restrict__ o)
{
  __shared__ float os[16][260];
  const int tile = blockIdx.x;
  const int b = tile / NT;
  const int p0 = (tile % NT) * 16;
  const int t = threadIdx.x;
  {
    const int p = t >> 4, c0 = (t & 15) * 16;
    const float4* src = (const float4*)(oattn + ((size_t)(b * NN) + p0 + p) * C + c0);
    float4* dst = (float4*)(os[p] + c0);
#pragma unroll
    for (int g = 0; g < 4; ++g) dst[g] = src[g];
  }
  __syncthreads();

  const int oc = t;
  float acc[16];
  {
    const float bias = ob[oc];
#pragma unroll
    for (int p = 0; p < 16; ++p) acc[p] = bias;
  }
  const float4* wr = (const float4*)(ow + (size_t)oc * C);
  for (int k4 = 0; k4 < 64; ++k4) {
    const float4 w = wr[k4];
#pragma unroll
    for (int p = 0; p < 16; ++p) {
      const float4 v = *(const float4*)(os[p] + k4 * 4);
      acc[p] += w.x * v.x + w.y * v.y + w.z * v.z + w.w * v.w;
    }
  }
  const float4* xp4 = (const float4*)(x + ((size_t)b * C + oc) * NN + p0);
  float4* op4 = (float4*)(o + ((size_t)b * C + oc) * NN + p0);
#pragma unroll
  for (int g = 0; g < 4; ++g) {
    const float4 xv = xp4[g];
    op4[g] = make_float4(acc[g * 4 + 0] + xv.x, acc[g * 4 + 1] + xv.y,
                         acc[g * 4 + 2] + xv.z, acc[g * 4 + 3] + xv.w);
  }
}

// ---------------------------------------------------------------------------
// 6. BN stats: per-channel sum and sumsq over (B, H, W)
// ---------------------------------------------------------------------------
__global__ __launch_bounds__(256) void stats_kernel(
    const float* __restrict__ o, float* __restrict__ stats)
{
  const int c = blockIdx.x, t = threadIdx.x;
  float s = 0.f, sq = 0.f;
  for (int b = 0; b < BB; ++b) {
    const float* p = o + ((size_t)b * C + c) * NN;
    for (int idx = t; idx < NN; idx += 256) {
      const float v = p[idx];
      s += v; sq += v * v;
    }
  }
#pragma unroll
  for (int off = 32; off >= 1; off >>= 1) {
    s += __shfl_xor(s, off);
    sq += __shfl_xor(sq, off);
  }
  __shared__ float red[8];
  const int wv = t >> 6;
  if ((t & 63) == 0) { red[wv] = s; red[4 + wv] = sq; }
  __syncthreads();
  if (t == 0) {
    s = red[0] + red[1] + red[2] + red[3];
    sq = red[4] + red[5] + red[6] + red[7];
    stats[c] = s;
    stats[C + c] = sq;
  }
}

// ---------------------------------------------------------------------------
// 7. BN normalize -> d_out
// ---------------------------------------------------------------------------
__global__ __launch_bounds__(256) void bn_kernel(
    const float* __restrict__ o, const float* __restrict__ stats,
    const float* __restrict__ g, const float* __restrict__ bta,
    float* __restrict__ out)
{
  const size_t idx = (size_t)blockIdx.x * 256 + threadIdx.x;  // float4 index
  const float inv_n = 1.f / (float)(BB * NN);
  float4 v = ((const float4*)o)[idx];
  const int c = (int)((idx * 4 / NN) % C);
  const float mean = stats[c] * inv_n;
  const float var = stats[C + c] * inv_n - mean * mean;
  const float sc = rsqrtf(var + 1e-5f) * g[c];
  const float sh = bta[c] - mean * sc;
  v.x = v.x * sc + sh; v.y = v.y * sc + sh;
  v.z = v.z * sc + sh; v.w = v.w * sc + sh;
  ((float4*)out)[idx] = v;
}

// ---------------------------------------------------------------------------
extern "C" void kernel_launch(void* const* d_in, const int* in_sizes, int n_in,
                              void* d_out, int out_size, void* d_ws, size_t ws_size,
                              hipStream_t stream)
{
  const float* x    = (const float*)d_in[0];
  const float* hn   = (const float*)d_in[1];
  const float* w1   = (const float*)d_in[2];  const float* b1   = (const float*)d_in[3];
  const float* w2   = (const float*)d_in[4];  const float* b2   = (const float*)d_in[5];
  const float* wadj = (const float*)d_in[6];  const float* badj = (const float*)d_in[7];
  const float* tw1  = (const float*)d_in[8];  const float* tb1  = (const float*)d_in[9];
  const float* tw2  = (const float*)d_in[10]; const float* tb2  = (const float*)d_in[11];
  const float* qaw  = (const float*)d_in[12]; const float* qab  = (const float*)d_in[13];
  const float* kaw  = (const float*)d_in[14]; const float* kab  = (const float*)d_in[15];
  const float* vaw  = (const float*)d_in[16]; const float* vab  = (const float*)d_in[17];
  const float* qtw  = (const float*)d_in[18]; const float* qtb  = (const float*)d_in[19];
  const float* ktw  = (const float*)d_in[20]; const float* ktb  = (const float*)d_in[21];
  const float* vtw  = (const float*)d_in[22]; const float* vtb  = (const float*)d_in[23];
  const float* ow   = (const float*)d_in[24]; const float* obias= (const float*)d_in[25];
  const float* bng  = (const float*)d_in[26]; const float* bnb  = (const float*)d_in[27];

  // workspace plan (sequential attention branches through ONE Q/K/V set):
  //   [a f32 25.69MB][t1 f32 25.69MB][tt f32 25.69MB][Q h 12.85][K h 12.85][V h 12.85][stats]
  // peak = 115.6 MB.  oattn reuses a's slot (a dead after qkv#1);
  // pre-BN o reuses t1's slot (t1 dead after conv#2).
  char* ws = (char*)d_ws;
  const size_t TENS  = (size_t)BB * C * NN * sizeof(float);   // 25,690,112 B
  const size_t HTENS = (size_t)BB * NN * C * sizeof(__half);  // 12,845,056 B
  float* a   = (float*)(ws);
  float* t1  = (float*)(ws + TENS);
  float* tt  = (float*)(ws + 2 * TENS);
  __half* Q  = (__half*)(ws + 3 * TENS);
  __half* K  = (__half*)(ws + 3 * TENS + 1 * HTENS);
  __half* V  = (__half*)(ws + 3 * TENS + 2 * HTENS);
  float* stats = (float*)(ws + 3 * TENS + 3 * HTENS);         // 512 floats

  const int PIX_TILES = BB * NT;      // 1568
  const int CONV_BLKS = BB * HH * 4;  // 1792

  attr_kernel<<<PIX_TILES, 256, 0, stream>>>(x, w1, b1, w2, b2, wadj, badj, a);
  conv3x3_kernel<<<CONV_BLKS, 256, 0, stream>>>(hn, tw1, tb1, nullptr, t1, 0, 1);
  conv3x3_kernel<<<CONV_BLKS, 256, 0, stream>>>(t1, tw2, tb2, a, tt, 1, 0);  // convT taps, *a fused

  // attr attention
  qkv_kernel<<<PIX_TILES, 256, 0, stream>>>(a, qaw, qab, kaw, kab, vaw, vab, Q, K, V, 0.5f);
  float* oattn = a;   // a's slot is dead once qkv#1 completed (stream-ordered)
  flash_kernel<<<PIX_TILES, 256, 0, stream>>>(Q, K, V, oattn, 0);
  // tex attention (reuse Q/K/V slots)
  qkv_kernel<<<PIX_TILES, 256, 0, stream>>>(tt, qtw, qtb, ktw, ktb, vtw, vtb, Q, K, V, 0.5f);
  flash_kernel<<<PIX_TILES, 256, 0, stream>>>(Q, K, V, oattn, 1);

  float* o = t1;      // t1 dead after conv#2
  outconv_kernel<<<PIX_TILES, 256, 0, stream>>>(oattn, ow, obias, x, o);
  stats_kernel<<<C, 256, 0, stream>>>(o, stats);
  bn_kernel<<<(BB * C * NN / 4) / 256, 256, 0, stream>>>(o, stats, bng, bnb, (float*)d_out);
}

// Round 3
// 6920.976 us; speedup vs baseline: 2.0623x; 2.0623x over previous
//
#include <hip/hip_runtime.h>
#include <hip/hip_fp16.h>

#define BB 8
#define C 256
#define HH 56
#define WW 56
#define NN 3136      // HH*WW
#define RR 16
#define NT (NN/16)   // 196 pixel-tiles per image

typedef _Float16 half8 __attribute__((ext_vector_type(8)));
typedef float floatx4 __attribute__((ext_vector_type(4)));

// ---------------------------------------------------------------------------
// 1. attr branch fused: a = adj( concat( relu(W2 relu(W1 x)), x ) )
// ---------------------------------------------------------------------------
__global__ __launch_bounds__(256) void attr_kernel(
    const float* __restrict__ x,
    const float* __restrict__ w1, const float* __restrict__ b1,
    const float* __restrict__ w2, const float* __restrict__ b2,
    const float* __restrict__ wadj, const float* __restrict__ badj,
    float* __restrict__ a_out)
{
  __shared__ float xs[C][20];
  __shared__ float a2s[C][20];
  __shared__ float a1s[RR][20];
  const int tile = blockIdx.x;
  const int b = tile / NT;
  const int p0 = (tile % NT) * 16;
  const int t = threadIdx.x;

  {
    const float* xb = x + ((size_t)b * C + t) * NN + p0;
    const float4* xb4 = (const float4*)xb;
    float* row = xs[t];
#pragma unroll
    for (int g = 0; g < 4; ++g) {
      float4 v = xb4[g];
      row[g * 4 + 0] = v.x; row[g * 4 + 1] = v.y;
      row[g * 4 + 2] = v.z; row[g * 4 + 3] = v.w;
    }
  }
  __syncthreads();

  {
    const int r = t & 15, pp = t >> 4;
    float acc = b1[r];
    const float* wr = w1 + r * C;
    for (int c = 0; c < C; ++c) acc += wr[c] * xs[c][pp];
    a1s[r][pp] = fmaxf(acc, 0.f);
  }
  __syncthreads();

  {
    const int o = t;
    float acc[16];
    const float bias = b2[o];
#pragma unroll
    for (int p = 0; p < 16; ++p) acc[p] = bias;
    const float* wr = w2 + o * RR;
    for (int k = 0; k < RR; ++k) {
      const float w = wr[k];
#pragma unroll
      for (int p = 0; p < 16; ++p) acc[p] += w * a1s[k][p];
    }
    float* row = a2s[o];
#pragma unroll
    for (int p = 0; p < 16; ++p) row[p] = fmaxf(acc[p], 0.f);
  }
  __syncthreads();

  {
    const int o = t;
    float acc[16];
    const float bias = badj[o];
#pragma unroll
    for (int p = 0; p < 16; ++p) acc[p] = bias;
    const float* wr = wadj + (size_t)o * (2 * C);
    for (int k = 0; k < C; ++k) {
      const float w = wr[k];
      const float4* ar = (const float4*)a2s[k];
#pragma unroll
      for (int g = 0; g < 4; ++g) {
        float4 v = ar[g];
        acc[g * 4 + 0] += w * v.x; acc[g * 4 + 1] += w * v.y;
        acc[g * 4 + 2] += w * v.z; acc[g * 4 + 3] += w * v.w;
      }
    }
    for (int k = 0; k < C; ++k) {
      const float w = wr[C + k];
      const float4* xr = (const float4*)xs[k];
#pragma unroll
      for (int g = 0; g < 4; ++g) {
        float4 v = xr[g];
        acc[g * 4 + 0] += w * v.x; acc[g * 4 + 1] += w * v.y;
        acc[g * 4 + 2] += w * v.z; acc[g * 4 + 3] += w * v.w;
      }
    }
    float* op = a_out + ((size_t)b * C + o) * NN + p0;
    float4* op4 = (float4*)op;
#pragma unroll
    for (int g = 0; g < 4; ++g)
      op4[g] = make_float4(acc[g * 4 + 0], acc[g * 4 + 1], acc[g * 4 + 2], acc[g * 4 + 3]);
  }
}

// ---------------------------------------------------------------------------
// 2. conv3x3 (pad 1). flip=1 -> taps W[o][c][2-ky][2-kx] (JAX conv_transpose
//    with IOHW + transpose_kernel=True == spatial flip only).
// ---------------------------------------------------------------------------
__global__ __launch_bounds__(256) void conv3x3_kernel(
    const float* __restrict__ in, const float* __restrict__ w,
    const float* __restrict__ bias, const float* __restrict__ mul,
    float* __restrict__ out, int flip, int do_relu)
{
  __shared__ float ins[C][3][16];
  const int bid = blockIdx.x;
  const int b = bid / (HH * 4);
  const int rem = bid % (HH * 4);
  const int h = rem >> 2;
  const int w0 = (rem & 3) * 14;
  const int t = threadIdx.x;

  {
    const float* ib = in + ((size_t)b * C + t) * NN;
#pragma unroll
    for (int dy = 0; dy < 3; ++dy) {
      const int gh = h + dy - 1;
      const bool rowok = (gh >= 0 && gh < HH);
#pragma unroll
      for (int j = 0; j < 16; ++j) {
        const int gw = w0 - 1 + j;
        float v = 0.f;
        if (rowok && gw >= 0 && gw < WW) v = ib[gh * WW + gw];
        ins[t][dy][j] = v;
      }
    }
  }
  __syncthreads();

  const int o = t;
  float acc[14];
#pragma unroll
  for (int p = 0; p < 14; ++p) acc[p] = 0.f;

  for (int c = 0; c < C; ++c) {
    const float* wp = w + ((size_t)o * C + c) * 9;
#pragma unroll
    for (int dy = 0; dy < 3; ++dy) {
      float r[16];
      const float* rr = ins[c][dy];
#pragma unroll
      for (int j = 0; j < 16; ++j) r[j] = rr[j];
      float wA, wB, wC_;
      if (!flip) {
        wA = wp[dy * 3 + 0]; wB = wp[dy * 3 + 1]; wC_ = wp[dy * 3 + 2];
      } else {
        wA = wp[(2 - dy) * 3 + 2]; wB = wp[(2 - dy) * 3 + 1]; wC_ = wp[(2 - dy) * 3 + 0];
      }
#pragma unroll
      for (int p = 0; p < 14; ++p)
        acc[p] += wA * r[p] + wB * r[p + 1] + wC_ * r[p + 2];
    }
  }

  const float bo = bias[o];
  const int pbase = h * WW + w0;
  float* op = out + ((size_t)b * C + o) * NN + pbase;
  if (mul != nullptr) {
    const float* mp = mul + ((size_t)b * C + o) * NN + pbase;
#pragma unroll
    for (int p = 0; p < 14; ++p) op[p] = (acc[p] + bo) * mp[p];
  } else if (do_relu) {
#pragma unroll
    for (int p = 0; p < 14; ++p) op[p] = fmaxf(acc[p] + bo, 0.f);
  } else {
#pragma unroll
    for (int p = 0; p < 14; ++p) op[p] = acc[p] + bo;
  }
}

// ---------------------------------------------------------------------------
// 3. fused Q/K/V linears: src [B][C][N] -> Q,K fp16 [B][N][C], Vt fp16 [B][C][N]
//    V pre-scaled by vscale (folds ALPHA=0.5). Vt transposed for MFMA PV.
// ---------------------------------------------------------------------------
__global__ __launch_bounds__(256) void qkv_kernel(
    const float* __restrict__ src,
    const float* __restrict__ wq, const float* __restrict__ bq,
    const float* __restrict__ wk, const float* __restrict__ bk,
    const float* __restrict__ wv, const float* __restrict__ bv,
    __half* __restrict__ Q, __half* __restrict__ K, __half* __restrict__ Vt,
    float vscale)
{
  __shared__ float ss[C][20];
  const int tile = blockIdx.x;
  const int b = tile / NT;
  const int p0 = (tile % NT) * 16;
  const int t = threadIdx.x;
  {
    const float4* sb = (const float4*)(src + ((size_t)b * C + t) * NN + p0);
    float* row = ss[t];
#pragma unroll
    for (int g = 0; g < 4; ++g) {
      float4 v = sb[g];
      row[g * 4 + 0] = v.x; row[g * 4 + 1] = v.y;
      row[g * 4 + 2] = v.z; row[g * 4 + 3] = v.w;
    }
  }
  __syncthreads();

  const int o = t;
  float aq[16], ak[16], av[16];
  {
    const float q0 = bq[o], k0 = bk[o], v0 = bv[o];
#pragma unroll
    for (int p = 0; p < 16; ++p) { aq[p] = q0; ak[p] = k0; av[p] = v0; }
  }
  const float* wqr = wq + o * C;
  const float* wkr = wk + o * C;
  const float* wvr = wv + o * C;
  for (int k = 0; k < C; ++k) {
    const float fq = wqr[k], fk = wkr[k], fv = wvr[k];
    const float4* sr = (const float4*)ss[k];
#pragma unroll
    for (int g = 0; g < 4; ++g) {
      float4 s = sr[g];
      aq[g * 4 + 0] += fq * s.x; aq[g * 4 + 1] += fq * s.y; aq[g * 4 + 2] += fq * s.z; aq[g * 4 + 3] += fq * s.w;
      ak[g * 4 + 0] += fk * s.x; ak[g * 4 + 1] += fk * s.y; ak[g * 4 + 2] += fk * s.z; ak[g * 4 + 3] += fk * s.w;
      av[g * 4 + 0] += fv * s.x; av[g * 4 + 1] += fv * s.y; av[g * 4 + 2] += fv * s.z; av[g * 4 + 3] += fv * s.w;
    }
  }
#pragma unroll
  for (int p = 0; p < 16; ++p) {
    const size_t base = ((size_t)(b * NN) + p0 + p) * C + o;
    Q[base] = __float2half(aq[p]);
    K[base] = __float2half(ak[p]);
  }
  // Vt[b][o][p0..p0+16]: 32B contiguous per thread
  __align__(16) __half hv[16];
#pragma unroll
  for (int p = 0; p < 16; ++p) hv[p] = __float2half(av[p] * vscale);
  __half* vtp = Vt + ((size_t)(b * C) + o) * NN + p0;
  ((uint4*)vtp)[0] = ((uint4*)hv)[0];
  ((uint4*)vtp)[1] = ((uint4*)hv)[1];
}

// ---------------------------------------------------------------------------
// 4. MFMA flash attention (16x16x32 f16).
//    Block = 4 waves, 32 q-rows. Waves (0,2) own rows 0-15, (1,3) rows 16-31.
//    Within a pair, wave role 0 takes even 64-key blocks, role 1 odd; the two
//    partial online-softmax states merge through LDS at the end.
//    K frags + Vt frags load straight from global (L2-resident); Q in regs.
// ---------------------------------------------------------------------------
__global__ __launch_bounds__(256) void flash2_kernel(
    const __half* __restrict__ Qg, const __half* __restrict__ Kg,
    const __half* __restrict__ Vtg, float* __restrict__ O, int accumulate)
{
  __shared__ __half Pbuf[4][16][68];    // [wave][q-row][key] pad 68: conflict-free
  __shared__ float Obuf[2][16][258];    // merge buffer per pair
  __shared__ float mlb[2][2][16];

  const int bid = blockIdx.x;
  const int b = bid / 98;
  const int q0 = (bid % 98) * 32;
  const int t = threadIdx.x;
  const int w = t >> 6;
  const int lane = t & 63;
  const int col = lane & 15;
  const int quad = lane >> 4;
  const int pairid = w & 1;   // which 16 q-rows
  const int role = w >> 1;    // which key strip

  // Q fragments: A[m=col][k=quad*8+j], rows q0 + pairid*16 + col
  const _Float16* Qp = (const _Float16*)Qg +
      ((size_t)(b * NN) + q0 + pairid * 16 + col) * C + quad * 8;
  half8 Qf[8];
#pragma unroll
  for (int s = 0; s < 8; ++s) Qf[s] = *(const half8*)(Qp + s * 32);

  floatx4 Ov[16];
#pragma unroll
  for (int n = 0; n < 16; ++n) Ov[n] = (floatx4){0.f, 0.f, 0.f, 0.f};
  float m[4] = {-1e30f, -1e30f, -1e30f, -1e30f};
  float l[4] = {0.f, 0.f, 0.f, 0.f};

  const _Float16* Kb = (const _Float16*)Kg + (size_t)(b * NN) * C;
  const _Float16* Vb = (const _Float16*)Vtg + (size_t)(b * C) * NN;

  for (int kb = role; kb < 49; kb += 2) {
    const int key0 = kb * 64;
    // ---- S = Q·K^T for 64 keys (4 n-tiles) ----
    floatx4 Sv[4];
#pragma unroll
    for (int nt = 0; nt < 4; ++nt) {
      floatx4 acc = (floatx4){0.f, 0.f, 0.f, 0.f};
      const _Float16* kp = Kb + (size_t)(key0 + nt * 16 + col) * C + quad * 8;
#pragma unroll
      for (int s = 0; s < 8; ++s) {
        half8 bf = *(const half8*)(kp + s * 32);
        acc = __builtin_amdgcn_mfma_f32_16x16x32_f16(Qf[s], bf, acc, 0, 0, 0);
      }
      Sv[nt] = acc * 0.0625f;  // 1/sqrt(256)
    }
    // ---- online softmax: rows = quad*4+r, cols across (nt, lane&15) ----
    float f[4];
#pragma unroll
    for (int r = 0; r < 4; ++r) {
      float v = fmaxf(fmaxf(Sv[0][r], Sv[1][r]), fmaxf(Sv[2][r], Sv[3][r]));
      v = fmaxf(v, __shfl_xor(v, 1));
      v = fmaxf(v, __shfl_xor(v, 2));
      v = fmaxf(v, __shfl_xor(v, 4));
      v = fmaxf(v, __shfl_xor(v, 8));
      const float mn = fmaxf(m[r], v);
      f[r] = __expf(m[r] - mn);
      m[r] = mn;
    }
    float rowsum[4] = {0.f, 0.f, 0.f, 0.f};
#pragma unroll
    for (int nt = 0; nt < 4; ++nt) {
#pragma unroll
      for (int r = 0; r < 4; ++r) {
        const float p = __expf(Sv[nt][r] - m[r]);
        Sv[nt][r] = p;
        rowsum[r] += p;
      }
    }
#pragma unroll
    for (int r = 0; r < 4; ++r) {
      float s = rowsum[r];
      s += __shfl_xor(s, 1);
      s += __shfl_xor(s, 2);
      s += __shfl_xor(s, 4);
      s += __shfl_xor(s, 8);
      l[r] = l[r] * f[r] + s;
    }
    // ---- write P (fp16) to LDS in A-operand-friendly layout ----
#pragma unroll
    for (int nt = 0; nt < 4; ++nt)
#pragma unroll
      for (int r = 0; r < 4; ++r)
        Pbuf[w][quad * 4 + r][nt * 16 + col] = __float2half(Sv[nt][r]);
    // ---- rescale O ----
    const floatx4 fv = {f[0], f[1], f[2], f[3]};
#pragma unroll
    for (int n = 0; n < 16; ++n) Ov[n] *= fv;
    // ---- O += P · V  (A = P from LDS, B = Vt frags from global) ----
    const half8 pa0 = *(const half8*)&Pbuf[w][col][quad * 8];
    const half8 pa1 = *(const half8*)&Pbuf[w][col][32 + quad * 8];
#pragma unroll
    for (int nt2 = 0; nt2 < 16; ++nt2) {
      const _Float16* vp = Vb + (size_t)(nt2 * 16 + col) * NN + key0 + quad * 8;
      const half8 bv0 = *(const half8*)vp;
      const half8 bv1 = *(const half8*)(vp + 32);
      Ov[nt2] = __builtin_amdgcn_mfma_f32_16x16x32_f16(pa0, bv0, Ov[nt2], 0, 0, 0);
      Ov[nt2] = __builtin_amdgcn_mfma_f32_16x16x32_f16(pa1, bv1, Ov[nt2], 0, 0, 0);
    }
  }

  // ---- merge the two key-strips of each pair ----
  if (role == 1) {
#pragma unroll
    for (int nt2 = 0; nt2 < 16; ++nt2)
#pragma unroll
      for (int r = 0; r < 4; ++r)
        Obuf[pairid][quad * 4 + r][nt2 * 16 + col] = Ov[nt2][r];
    if (col == 0) {
#pragma unroll
      for (int r = 0; r < 4; ++r) {
        mlb[pairid][0][quad * 4 + r] = m[r];
        mlb[pairid][1][quad * 4 + r] = l[r];
      }
    }
  }
  __syncthreads();
  if (role == 0) {
    float f1[4], f2[4], inv[4];
#pragma unroll
    for (int r = 0; r < 4; ++r) {
      const float m2 = mlb[pairid][0][quad * 4 + r];
      const float l2 = mlb[pairid][1][quad * 4 + r];
      const float M = fmaxf(m[r], m2);
      f1[r] = __expf(m[r] - M);
      f2[r] = __expf(m2 - M);
      inv[r] = 1.f / (l[r] * f1[r] + l2 * f2[r]);
    }
#pragma unroll
    for (int nt2 = 0; nt2 < 16; ++nt2) {
#pragma unroll
      for (int r = 0; r < 4; ++r) {
        const float val =
            (Ov[nt2][r] * f1[r] +
             Obuf[pairid][quad * 4 + r][nt2 * 16 + col] * f2[r]) * inv[r];
        float* dst = O + ((size_t)(b * NN) + q0 + pairid * 16 + quad * 4 + r) * C +
                     nt2 * 16 + col;
        if (accumulate) *dst += val; else *dst = val;
      }
    }
  }
}

// ---------------------------------------------------------------------------
// 5. out 1x1 conv + residual
// ---------------------------------------------------------------------------
__global__ __launch_bounds__(256) void outconv_kernel(
    const float* __restrict__ oattn, const float* __restrict__ ow,
    const float* __restrict__ ob, const float* __restrict__ x,
    float* __restrict__ o)
{
  __shared__ float os[16][260];
  const int tile = blockIdx.x;
  const int b = tile / NT;
  const int p0 = (tile % NT) * 16;
  const int t = threadIdx.x;
  {
    const int p = t >> 4, c0 = (t & 15) * 16;
    const float4* src = (const float4*)(oattn + ((size_t)(b * NN) + p0 + p) * C + c0);
    float4* dst = (float4*)(os[p] + c0);
#pragma unroll
    for (int g = 0; g < 4; ++g) dst[g] = src[g];
  }
  __syncthreads();

  const int oc = t;
  float acc[16];
  {
    const float bias = ob[oc];
#pragma unroll
    for (int p = 0; p < 16; ++p) acc[p] = bias;
  }
  const float4* wr = (const float4*)(ow + (size_t)oc * C);
  for (int k4 = 0; k4 < 64; ++k4) {
    const float4 w = wr[k4];
#pragma unroll
    for (int p = 0; p < 16; ++p) {
      const float4 v = *(const float4*)(os[p] + k4 * 4);
      acc[p] += w.x * v.x + w.y * v.y + w.z * v.z + w.w * v.w;
    }
  }
  const float4* xp4 = (const float4*)(x + ((size_t)b * C + oc) * NN + p0);
  float4* op4 = (float4*)(o + ((size_t)b * C + oc) * NN + p0);
#pragma unroll
  for (int g = 0; g < 4; ++g) {
    const float4 xv = xp4[g];
    op4[g] = make_float4(acc[g * 4 + 0] + xv.x, acc[g * 4 + 1] + xv.y,
                         acc[g * 4 + 2] + xv.z, acc[g * 4 + 3] + xv.w);
  }
}

// ---------------------------------------------------------------------------
// 6. BN stats
// ---------------------------------------------------------------------------
__global__ __launch_bounds__(256) void stats_kernel(
    const float* __restrict__ o, float* __restrict__ stats)
{
  const int c = blockIdx.x, t = threadIdx.x;
  float s = 0.f, sq = 0.f;
  for (int b = 0; b < BB; ++b) {
    const float* p = o + ((size_t)b * C + c) * NN;
    for (int idx = t; idx < NN; idx += 256) {
      const float v = p[idx];
      s += v; sq += v * v;
    }
  }
#pragma unroll
  for (int off = 32; off >= 1; off >>= 1) {
    s += __shfl_xor(s, off);
    sq += __shfl_xor(sq, off);
  }
  __shared__ float red[8];
  const int wv = t >> 6;
  if ((t & 63) == 0) { red[wv] = s; red[4 + wv] = sq; }
  __syncthreads();
  if (t == 0) {
    s = red[0] + red[1] + red[2] + red[3];
    sq = red[4] + red[5] + red[6] + red[7];
    stats[c] = s;
    stats[C + c] = sq;
  }
}

// ---------------------------------------------------------------------------
// 7. BN normalize -> d_out
// ---------------------------------------------------------------------------
__global__ __launch_bounds__(256) void bn_kernel(
    const float* __restrict__ o, const float* __restrict__ stats,
    const float* __restrict__ g, const float* __restrict__ bta,
    float* __restrict__ out)
{
  const size_t idx = (size_t)blockIdx.x * 256 + threadIdx.x;
  const float inv_n = 1.f / (float)(BB * NN);
  float4 v = ((const float4*)o)[idx];
  const int c = (int)((idx * 4 / NN) % C);
  const float mean = stats[c] * inv_n;
  const float var = stats[C + c] * inv_n - mean * mean;
  const float sc = rsqrtf(var + 1e-5f) * g[c];
  const float sh = bta[c] - mean * sc;
  v.x = v.x * sc + sh; v.y = v.y * sc + sh;
  v.z = v.z * sc + sh; v.w = v.w * sc + sh;
  ((float4*)out)[idx] = v;
}

// ---------------------------------------------------------------------------
extern "C" void kernel_launch(void* const* d_in, const int* in_sizes, int n_in,
                              void* d_out, int out_size, void* d_ws, size_t ws_size,
                              hipStream_t stream)
{
  const float* x    = (const float*)d_in[0];
  const float* hn   = (const float*)d_in[1];
  const float* w1   = (const float*)d_in[2];  const float* b1   = (const float*)d_in[3];
  const float* w2   = (const float*)d_in[4];  const float* b2   = (const float*)d_in[5];
  const float* wadj = (const float*)d_in[6];  const float* badj = (const float*)d_in[7];
  const float* tw1  = (const float*)d_in[8];  const float* tb1  = (const float*)d_in[9];
  const float* tw2  = (const float*)d_in[10]; const float* tb2  = (const float*)d_in[11];
  const float* qaw  = (const float*)d_in[12]; const float* qab  = (const float*)d_in[13];
  const float* kaw  = (const float*)d_in[14]; const float* kab  = (const float*)d_in[15];
  const float* vaw  = (const float*)d_in[16]; const float* vab  = (const float*)d_in[17];
  const float* qtw  = (const float*)d_in[18]; const float* qtb  = (const float*)d_in[19];
  const float* ktw  = (const float*)d_in[20]; const float* ktb  = (const float*)d_in[21];
  const float* vtw  = (const float*)d_in[22]; const float* vtb  = (const float*)d_in[23];
  const float* ow   = (const float*)d_in[24]; const float* obias= (const float*)d_in[25];
  const float* bng  = (const float*)d_in[26]; const float* bnb  = (const float*)d_in[27];

  // ws: [a][t1][tt] f32 + [Q][K][Vt] f16 + stats  (peak ~115.6 MB)
  char* ws = (char*)d_ws;
  const size_t TENS  = (size_t)BB * C * NN * sizeof(float);   // 25,690,112 B
  const size_t HTENS = (size_t)BB * NN * C * sizeof(__half);  // 12,845,056 B
  float* a   = (float*)(ws);
  float* t1  = (float*)(ws + TENS);
  float* tt  = (float*)(ws + 2 * TENS);
  __half* Q  = (__half*)(ws + 3 * TENS);
  __half* K  = (__half*)(ws + 3 * TENS + 1 * HTENS);
  __half* Vt = (__half*)(ws + 3 * TENS + 2 * HTENS);
  float* stats = (float*)(ws + 3 * TENS + 3 * HTENS);

  const int PIX_TILES = BB * NT;      // 1568
  const int CONV_BLKS = BB * HH * 4;  // 1792
  const int FLASH_BLKS = BB * (NN / 32);  // 784

  attr_kernel<<<PIX_TILES, 256, 0, stream>>>(x, w1, b1, w2, b2, wadj, badj, a);
  conv3x3_kernel<<<CONV_BLKS, 256, 0, stream>>>(hn, tw1, tb1, nullptr, t1, 0, 1);
  conv3x3_kernel<<<CONV_BLKS, 256, 0, stream>>>(t1, tw2, tb2, a, tt, 1, 0);

  qkv_kernel<<<PIX_TILES, 256, 0, stream>>>(a, qaw, qab, kaw, kab, vaw, vab, Q, K, Vt, 0.5f);
  float* oattn = a;   // a dead after qkv#1
  flash2_kernel<<<FLASH_BLKS, 256, 0, stream>>>(Q, K, Vt, oattn, 0);
  qkv_kernel<<<PIX_TILES, 256, 0, stream>>>(tt, qtw, qtb, ktw, ktb, vtw, vtb, Q, K, Vt, 0.5f);
  flash2_kernel<<<FLASH_BLKS, 256, 0, stream>>>(Q, K, Vt, oattn, 1);

  float* o = t1;      // t1 dead after conv#2
  outconv_kernel<<<PIX_TILES, 256, 0, stream>>>(oattn, ow, obias, x, o);
  stats_kernel<<<C, 256, 0, stream>>>(o, stats);
  bn_kernel<<<(BB * C * NN / 4) / 256, 256, 0, stream>>>(o, stats, bng, bnb, (float*)d_out);
}

// Round 4
// 3728.650 us; speedup vs baseline: 3.8280x; 1.8562x over previous
//
#include <hip/hip_runtime.h>
#include <hip/hip_fp16.h>

#define BB 8
#define C 256
#define HH 56
#define WW 56
#define NN 3136      // HH*WW
#define RR 16
#define NT (NN/16)   // 196 pixel-tiles per image
#define PW 58        // padded spatial width/height

typedef _Float16 half8 __attribute__((ext_vector_type(8)));
typedef float floatx4 __attribute__((ext_vector_type(4)));

// ---------------------------------------------------------------------------
// 1. attr branch fused: a = adj( concat( relu(W2 relu(W1 x)), x ) )
// ---------------------------------------------------------------------------
__global__ __launch_bounds__(256) void attr_kernel(
    const float* __restrict__ x,
    const float* __restrict__ w1, const float* __restrict__ b1,
    const float* __restrict__ w2, const float* __restrict__ b2,
    const float* __restrict__ wadj, const float* __restrict__ badj,
    float* __restrict__ a_out)
{
  __shared__ float xs[C][20];
  __shared__ float a2s[C][20];
  __shared__ float a1s[RR][20];
  const int tile = blockIdx.x;
  const int b = tile / NT;
  const int p0 = (tile % NT) * 16;
  const int t = threadIdx.x;

  {
    const float* xb = x + ((size_t)b * C + t) * NN + p0;
    const float4* xb4 = (const float4*)xb;
    float* row = xs[t];
#pragma unroll
    for (int g = 0; g < 4; ++g) {
      float4 v = xb4[g];
      row[g * 4 + 0] = v.x; row[g * 4 + 1] = v.y;
      row[g * 4 + 2] = v.z; row[g * 4 + 3] = v.w;
    }
  }
  __syncthreads();

  {
    const int r = t & 15, pp = t >> 4;
    float acc = b1[r];
    const float* wr = w1 + r * C;
    for (int c = 0; c < C; ++c) acc += wr[c] * xs[c][pp];
    a1s[r][pp] = fmaxf(acc, 0.f);
  }
  __syncthreads();

  {
    const int o = t;
    float acc[16];
    const float bias = b2[o];
#pragma unroll
    for (int p = 0; p < 16; ++p) acc[p] = bias;
    const float* wr = w2 + o * RR;
    for (int k = 0; k < RR; ++k) {
      const float w = wr[k];
#pragma unroll
      for (int p = 0; p < 16; ++p) acc[p] += w * a1s[k][p];
    }
    float* row = a2s[o];
#pragma unroll
    for (int p = 0; p < 16; ++p) row[p] = fmaxf(acc[p], 0.f);
  }
  __syncthreads();

  {
    const int o = t;
    float acc[16];
    const float bias = badj[o];
#pragma unroll
    for (int p = 0; p < 16; ++p) acc[p] = bias;
    const float* wr = wadj + (size_t)o * (2 * C);
    for (int k = 0; k < C; ++k) {
      const float w = wr[k];
      const float4* ar = (const float4*)a2s[k];
#pragma unroll
      for (int g = 0; g < 4; ++g) {
        float4 v = ar[g];
        acc[g * 4 + 0] += w * v.x; acc[g * 4 + 1] += w * v.y;
        acc[g * 4 + 2] += w * v.z; acc[g * 4 + 3] += w * v.w;
      }
    }
    for (int k = 0; k < C; ++k) {
      const float w = wr[C + k];
      const float4* xr = (const float4*)xs[k];
#pragma unroll
      for (int g = 0; g < 4; ++g) {
        float4 v = xr[g];
        acc[g * 4 + 0] += w * v.x; acc[g * 4 + 1] += w * v.y;
        acc[g * 4 + 2] += w * v.z; acc[g * 4 + 3] += w * v.w;
      }
    }
    float* op = a_out + ((size_t)b * C + o) * NN + p0;
    float4* op4 = (float4*)op;
#pragma unroll
    for (int g = 0; g < 4; ++g)
      op4[g] = make_float4(acc[g * 4 + 0], acc[g * 4 + 1], acc[g * 4 + 2], acc[g * 4 + 3]);
  }
}

// ---------------------------------------------------------------------------
// 2a. weight prep: w1h[tap][o][c] = tw1[o][c][tap] (fp16)
//     w2h[tap][o][c] = tw2[o][c][8-tap]  (convT spatial flip folded in)
// ---------------------------------------------------------------------------
__global__ __launch_bounds__(256) void wprep_kernel(
    const float* __restrict__ tw1, const float* __restrict__ tw2,
    _Float16* __restrict__ w1h, _Float16* __restrict__ w2h)
{
  const int i = blockIdx.x * 256 + threadIdx.x;   // over 9*256*256
  const int tap = i >> 16;
  const int rem = i & 65535;
  const int o = rem >> 8;
  const int c = rem & 255;
  w1h[i] = (_Float16)tw1[((size_t)o * C + c) * 9 + tap];
  w2h[i] = (_Float16)tw2[((size_t)o * C + c) * 9 + (8 - tap)];
}

// ---------------------------------------------------------------------------
// 2b. zero the pad border of both padded-NHWC fp16 buffers
// ---------------------------------------------------------------------------
__global__ __launch_bounds__(256) void padzero_kernel(
    _Float16* __restrict__ buf1, _Float16* __restrict__ buf2)
{
  const int bid = blockIdx.x;                 // 2 * BB * PW
  _Float16* buf = (bid < BB * PW) ? buf1 : buf2;
  const int rb = bid % (BB * PW);
  const int b = rb / PW, r = rb % PW;
  _Float16* row = buf + ((size_t)b * PW + r) * PW * C;
  const float4 z = make_float4(0.f, 0.f, 0.f, 0.f);
  if (r == 0 || r == PW - 1) {
    for (int i = threadIdx.x; i < PW * C / 8; i += 256) ((float4*)row)[i] = z;
  } else {
    const int i = threadIdx.x;
    if (i < 32) ((float4*)row)[i] = z;                       // col 0
    else if (i < 64) ((float4*)(row + (PW - 1) * C))[i - 32] = z;  // col 57
  }
}

// ---------------------------------------------------------------------------
// 2c. hn (fp32 NCHW) -> hnpad (fp16 padded NHWC) interior, via LDS transpose
// ---------------------------------------------------------------------------
__global__ __launch_bounds__(256) void hnprep_kernel(
    const float* __restrict__ hn, _Float16* __restrict__ hnpad)
{
  __shared__ float xs[C][17];
  const int tile = blockIdx.x;
  const int b = tile / NT;
  const int p0 = (tile % NT) * 16;
  const int t = threadIdx.x;
  {
    const float4* sb = (const float4*)(hn + ((size_t)b * C + t) * NN + p0);
    float* row = xs[t];
#pragma unroll
    for (int g = 0; g < 4; ++g) {
      float4 v = sb[g];
      row[g * 4 + 0] = v.x; row[g * 4 + 1] = v.y;
      row[g * 4 + 2] = v.z; row[g * 4 + 3] = v.w;
    }
  }
  __syncthreads();
  const int p = t >> 4, c0 = (t & 15) * 16;
  const int pg = p0 + p;
  const int h = pg / WW, w = pg % WW;
  __align__(16) _Float16 tmp[16];
#pragma unroll
  for (int j = 0; j < 16; ++j) tmp[j] = (_Float16)xs[c0 + j][p];
  _Float16* dst = hnpad + (((size_t)b * PW + h + 1) * PW + w + 1) * C + c0;
  ((uint4*)dst)[0] = ((uint4*)tmp)[0];
  ((uint4*)dst)[1] = ((uint4*)tmp)[1];
}

// ---------------------------------------------------------------------------
// 2d. conv3x3 as 9-tap MFMA GEMM.
//     in: padded NHWC fp16 [b][58][58][C]; w: [tap][o][c] fp16.
//     mode 0: out_h = relu(conv+bias) -> padded NHWC fp16 (interior only)
//     mode 1: out_f = (conv+bias) * amul -> fp32 NCHW
//     Block: (b, h, o-half). 4 waves x (2 m-tiles x 4 n-tiles); 64-px row tile,
//     pixels >=56 computed but masked on store (OOB reads land in masked cols).
// ---------------------------------------------------------------------------
__global__ __launch_bounds__(256) void conv_mfma_kernel(
    const _Float16* __restrict__ inpad, const _Float16* __restrict__ wh,
    const float* __restrict__ bias, const float* __restrict__ amul,
    _Float16* __restrict__ out_h, float* __restrict__ out_f, int mode)
{
  const int bid = blockIdx.x;          // BB*56*2
  const int ohalf = bid & 1;
  const int h = (bid >> 1) % HH;
  const int b = bid / (HH * 2);
  const int t = threadIdx.x;
  const int wave = t >> 6, lane = t & 63;
  const int col = lane & 15, quad = lane >> 4;
  const int o_base = ohalf * 128 + wave * 32;

  floatx4 acc[2][4];
#pragma unroll
  for (int mt = 0; mt < 2; ++mt)
#pragma unroll
    for (int nt = 0; nt < 4; ++nt) acc[mt][nt] = (floatx4){0.f, 0.f, 0.f, 0.f};

  const _Float16* inb = inpad + (size_t)b * PW * PW * C;

  for (int tap = 0; tap < 9; ++tap) {
    const int dy = tap / 3;
    const int dx = tap - dy * 3;
    const _Float16* wtap = wh + (size_t)tap * C * C + quad * 8;
    const _Float16* inrow = inb + ((size_t)(h + dy) * PW + dx + col) * C + quad * 8;
    for (int kc = 0; kc < 8; ++kc) {
      const int c0 = kc * 32;
      const half8 A0 = *(const half8*)(wtap + (size_t)(o_base + col) * C + c0);
      const half8 A1 = *(const half8*)(wtap + (size_t)(o_base + 16 + col) * C + c0);
#pragma unroll
      for (int nt = 0; nt < 4; ++nt) {
        const half8 Bv = *(const half8*)(inrow + (size_t)(nt * 16) * C + c0);
        acc[0][nt] = __builtin_amdgcn_mfma_f32_16x16x32_f16(A0, Bv, acc[0][nt], 0, 0, 0);
        acc[1][nt] = __builtin_amdgcn_mfma_f32_16x16x32_f16(A1, Bv, acc[1][nt], 0, 0, 0);
      }
    }
  }

  // epilogue: C-frag row (o) = quad*4+r, col (pixel) = nt*16+col
#pragma unroll
  for (int mt = 0; mt < 2; ++mt) {
    const int o = o_base + mt * 16 + quad * 4;
    const float* bp = bias + o;
    const float b0 = bp[0], b1_ = bp[1], b2_ = bp[2], b3 = bp[3];
    if (mode == 0) {
#pragma unroll
      for (int nt = 0; nt < 4; ++nt) {
        const int wpx = nt * 16 + col;
        if (wpx < WW) {
          __align__(8) _Float16 hv[4];
          hv[0] = (_Float16)fmaxf(acc[mt][nt][0] + b0, 0.f);
          hv[1] = (_Float16)fmaxf(acc[mt][nt][1] + b1_, 0.f);
          hv[2] = (_Float16)fmaxf(acc[mt][nt][2] + b2_, 0.f);
          hv[3] = (_Float16)fmaxf(acc[mt][nt][3] + b3, 0.f);
          _Float16* dst = out_h + (((size_t)b * PW + h + 1) * PW + wpx + 1) * C + o;
          *(uint2*)dst = *(uint2*)hv;
        }
      }
    } else {
#pragma unroll
      for (int nt = 0; nt < 4; ++nt) {
        const int wpx = nt * 16 + col;
        if (wpx < WW) {
          const int p = h * WW + wpx;
          const float bb[4] = {b0, b1_, b2_, b3};
#pragma unroll
          for (int r = 0; r < 4; ++r) {
            const size_t idx = ((size_t)(b * C + o + r)) * NN + p;
            out_f[idx] = (acc[mt][nt][r] + bb[r]) * amul[idx];
          }
        }
      }
    }
  }
}

// ---------------------------------------------------------------------------
// 3. fused Q/K/V linears: src [B][C][N] -> Q,K fp16 [B][N][C], Vt fp16 [B][C][N]
// ---------------------------------------------------------------------------
__global__ __launch_bounds__(256) void qkv_kernel(
    const float* __restrict__ src,
    const float* __restrict__ wq, const float* __restrict__ bq,
    const float* __restrict__ wk, const float* __restrict__ bk,
    const float* __restrict__ wv, const float* __restrict__ bv,
    __half* __restrict__ Q, __half* __restrict__ K, __half* __restrict__ Vt,
    float vscale)
{
  __shared__ float ss[C][20];
  const int tile = blockIdx.x;
  const int b = tile / NT;
  const int p0 = (tile % NT) * 16;
  const int t = threadIdx.x;
  {
    const float4* sb = (const float4*)(src + ((size_t)b * C + t) * NN + p0);
    float* row = ss[t];
#pragma unroll
    for (int g = 0; g < 4; ++g) {
      float4 v = sb[g];
      row[g * 4 + 0] = v.x; row[g * 4 + 1] = v.y;
      row[g * 4 + 2] = v.z; row[g * 4 + 3] = v.w;
    }
  }
  __syncthreads();

  const int o = t;
  float aq[16], ak[16], av[16];
  {
    const float q0 = bq[o], k0 = bk[o], v0 = bv[o];
#pragma unroll
    for (int p = 0; p < 16; ++p) { aq[p] = q0; ak[p] = k0; av[p] = v0; }
  }
  const float* wqr = wq + o * C;
  const float* wkr = wk + o * C;
  const float* wvr = wv + o * C;
  for (int k = 0; k < C; ++k) {
    const float fq = wqr[k], fk = wkr[k], fv = wvr[k];
    const float4* sr = (const float4*)ss[k];
#pragma unroll
    for (int g = 0; g < 4; ++g) {
      float4 s = sr[g];
      aq[g * 4 + 0] += fq * s.x; aq[g * 4 + 1] += fq * s.y; aq[g * 4 + 2] += fq * s.z; aq[g * 4 + 3] += fq * s.w;
      ak[g * 4 + 0] += fk * s.x; ak[g * 4 + 1] += fk * s.y; ak[g * 4 + 2] += fk * s.z; ak[g * 4 + 3] += fk * s.w;
      av[g * 4 + 0] += fv * s.x; av[g * 4 + 1] += fv * s.y; av[g * 4 + 2] += fv * s.z; av[g * 4 + 3] += fv * s.w;
    }
  }
#pragma unroll
  for (int p = 0; p < 16; ++p) {
    const size_t base = ((size_t)(b * NN) + p0 + p) * C + o;
    Q[base] = __float2half(aq[p]);
    K[base] = __float2half(ak[p]);
  }
  __align__(16) __half hv[16];
#pragma unroll
  for (int p = 0; p < 16; ++p) hv[p] = __float2half(av[p] * vscale);
  __half* vtp = Vt + ((size_t)(b * C) + o) * NN + p0;
  ((uint4*)vtp)[0] = ((uint4*)hv)[0];
  ((uint4*)vtp)[1] = ((uint4*)hv)[1];
}

// ---------------------------------------------------------------------------
// 4. MFMA flash attention (16x16x32 f16).
// ---------------------------------------------------------------------------
__global__ __launch_bounds__(256) void flash2_kernel(
    const __half* __restrict__ Qg, const __half* __restrict__ Kg,
    const __half* __restrict__ Vtg, float* __restrict__ O, int accumulate)
{
  __shared__ __half Pbuf[4][16][68];
  __shared__ float Obuf[2][16][258];
  __shared__ float mlb[2][2][16];

  const int bid = blockIdx.x;
  const int b = bid / 98;
  const int q0 = (bid % 98) * 32;
  const int t = threadIdx.x;
  const int w = t >> 6;
  const int lane = t & 63;
  const int col = lane & 15;
  const int quad = lane >> 4;
  const int pairid = w & 1;
  const int role = w >> 1;

  const _Float16* Qp = (const _Float16*)Qg +
      ((size_t)(b * NN) + q0 + pairid * 16 + col) * C + quad * 8;
  half8 Qf[8];
#pragma unroll
  for (int s = 0; s < 8; ++s) Qf[s] = *(const half8*)(Qp + s * 32);

  floatx4 Ov[16];
#pragma unroll
  for (int n = 0; n < 16; ++n) Ov[n] = (floatx4){0.f, 0.f, 0.f, 0.f};
  float m[4] = {-1e30f, -1e30f, -1e30f, -1e30f};
  float l[4] = {0.f, 0.f, 0.f, 0.f};

  const _Float16* Kb = (const _Float16*)Kg + (size_t)(b * NN) * C;
  const _Float16* Vb = (const _Float16*)Vtg + (size_t)(b * C) * NN;

  for (int kb = role; kb < 49; kb += 2) {
    const int key0 = kb * 64;
    floatx4 Sv[4];
#pragma unroll
    for (int nt = 0; nt < 4; ++nt) {
      floatx4 acc = (floatx4){0.f, 0.f, 0.f, 0.f};
      const _Float16* kp = Kb + (size_t)(key0 + nt * 16 + col) * C + quad * 8;
#pragma unroll
      for (int s = 0; s < 8; ++s) {
        half8 bf = *(const half8*)(kp + s * 32);
        acc = __builtin_amdgcn_mfma_f32_16x16x32_f16(Qf[s], bf, acc, 0, 0, 0);
      }
      Sv[nt] = acc * 0.0625f;
    }
    float f[4];
#pragma unroll
    for (int r = 0; r < 4; ++r) {
      float v = fmaxf(fmaxf(Sv[0][r], Sv[1][r]), fmaxf(Sv[2][r], Sv[3][r]));
      v = fmaxf(v, __shfl_xor(v, 1));
      v = fmaxf(v, __shfl_xor(v, 2));
      v = fmaxf(v, __shfl_xor(v, 4));
      v = fmaxf(v, __shfl_xor(v, 8));
      const float mn = fmaxf(m[r], v);
      f[r] = __expf(m[r] - mn);
      m[r] = mn;
    }
    float rowsum[4] = {0.f, 0.f, 0.f, 0.f};
#pragma unroll
    for (int nt = 0; nt < 4; ++nt) {
#pragma unroll
      for (int r = 0; r < 4; ++r) {
        const float p = __expf(Sv[nt][r] - m[r]);
        Sv[nt][r] = p;
        rowsum[r] += p;
      }
    }
#pragma unroll
    for (int r = 0; r < 4; ++r) {
      float s = rowsum[r];
      s += __shfl_xor(s, 1);
      s += __shfl_xor(s, 2);
      s += __shfl_xor(s, 4);
      s += __shfl_xor(s, 8);
      l[r] = l[r] * f[r] + s;
    }
#pragma unroll
    for (int nt = 0; nt < 4; ++nt)
#pragma unroll
      for (int r = 0; r < 4; ++r)
        Pbuf[w][quad * 4 + r][nt * 16 + col] = __float2half(Sv[nt][r]);
    const floatx4 fv = {f[0], f[1], f[2], f[3]};
#pragma unroll
    for (int n = 0; n < 16; ++n) Ov[n] *= fv;
    const half8 pa0 = *(const half8*)&Pbuf[w][col][quad * 8];
    const half8 pa1 = *(const half8*)&Pbuf[w][col][32 + quad * 8];
#pragma unroll
    for (int nt2 = 0; nt2 < 16; ++nt2) {
      const _Float16* vp = Vb + (size_t)(nt2 * 16 + col) * NN + key0 + quad * 8;
      const half8 bv0 = *(const half8*)vp;
      const half8 bv1 = *(const half8*)(vp + 32);
      Ov[nt2] = __builtin_amdgcn_mfma_f32_16x16x32_f16(pa0, bv0, Ov[nt2], 0, 0, 0);
      Ov[nt2] = __builtin_amdgcn_mfma_f32_16x16x32_f16(pa1, bv1, Ov[nt2], 0, 0, 0);
    }
  }

  if (role == 1) {
#pragma unroll
    for (int nt2 = 0; nt2 < 16; ++nt2)
#pragma unroll
      for (int r = 0; r < 4; ++r)
        Obuf[pairid][quad * 4 + r][nt2 * 16 + col] = Ov[nt2][r];
    if (col == 0) {
#pragma unroll
      for (int r = 0; r < 4; ++r) {
        mlb[pairid][0][quad * 4 + r] = m[r];
        mlb[pairid][1][quad * 4 + r] = l[r];
      }
    }
  }
  __syncthreads();
  if (role == 0) {
    float f1[4], f2[4], inv[4];
#pragma unroll
    for (int r = 0; r < 4; ++r) {
      const float m2 = mlb[pairid][0][quad * 4 + r];
      const float l2 = mlb[pairid][1][quad * 4 + r];
      const float M = fmaxf(m[r], m2);
      f1[r] = __expf(m[r] - M);
      f2[r] = __expf(m2 - M);
      inv[r] = 1.f / (l[r] * f1[r] + l2 * f2[r]);
    }
#pragma unroll
    for (int nt2 = 0; nt2 < 16; ++nt2) {
#pragma unroll
      for (int r = 0; r < 4; ++r) {
        const float val =
            (Ov[nt2][r] * f1[r] +
             Obuf[pairid][quad * 4 + r][nt2 * 16 + col] * f2[r]) * inv[r];
        float* dst = O + ((size_t)(b * NN) + q0 + pairid * 16 + quad * 4 + r) * C +
                     nt2 * 16 + col;
        if (accumulate) *dst += val; else *dst = val;
      }
    }
  }
}

// ---------------------------------------------------------------------------
// 5. out 1x1 conv + residual
// ---------------------------------------------------------------------------
__global__ __launch_bounds__(256) void outconv_kernel(
    const float* __restrict__ oattn, const float* __restrict__ ow,
    const float* __restrict__ ob, const float* __restrict__ x,
    float* __restrict__ o)
{
  __shared__ float os[16][260];
  const int tile = blockIdx.x;
  const int b = tile / NT;
  const int p0 = (tile % NT) * 16;
  const int t = threadIdx.x;
  {
    const int p = t >> 4, c0 = (t & 15) * 16;
    const float4* src = (const float4*)(oattn + ((size_t)(b * NN) + p0 + p) * C + c0);
    float4* dst = (float4*)(os[p] + c0);
#pragma unroll
    for (int g = 0; g < 4; ++g) dst[g] = src[g];
  }
  __syncthreads();

  const int oc = t;
  float acc[16];
  {
    const float bias = ob[oc];
#pragma unroll
    for (int p = 0; p < 16; ++p) acc[p] = bias;
  }
  const float4* wr = (const float4*)(ow + (size_t)oc * C);
  for (int k4 = 0; k4 < 64; ++k4) {
    const float4 w = wr[k4];
#pragma unroll
    for (int p = 0; p < 16; ++p) {
      const float4 v = *(const float4*)(os[p] + k4 * 4);
      acc[p] += w.x * v.x + w.y * v.y + w.z * v.z + w.w * v.w;
    }
  }
  const float4* xp4 = (const float4*)(x + ((size_t)b * C + oc) * NN + p0);
  float4* op4 = (float4*)(o + ((size_t)b * C + oc) * NN + p0);
#pragma unroll
  for (int g = 0; g < 4; ++g) {
    const float4 xv = xp4[g];
    op4[g] = make_float4(acc[g * 4 + 0] + xv.x, acc[g * 4 + 1] + xv.y,
                         acc[g * 4 + 2] + xv.z, acc[g * 4 + 3] + xv.w);
  }
}

// ---------------------------------------------------------------------------
// 6. BN stats
// ---------------------------------------------------------------------------
__global__ __launch_bounds__(256) void stats_kernel(
    const float* __restrict__ o, float* __restrict__ stats)
{
  const int c = blockIdx.x, t = threadIdx.x;
  float s = 0.f, sq = 0.f;
  for (int b = 0; b < BB; ++b) {
    const float* p = o + ((size_t)b * C + c) * NN;
    for (int idx = t; idx < NN; idx += 256) {
      const float v = p[idx];
      s += v; sq += v * v;
    }
  }
#pragma unroll
  for (int off = 32; off >= 1; off >>= 1) {
    s += __shfl_xor(s, off);
    sq += __shfl_xor(sq, off);
  }
  __shared__ float red[8];
  const int wv = t >> 6;
  if ((t & 63) == 0) { red[wv] = s; red[4 + wv] = sq; }
  __syncthreads();
  if (t == 0) {
    s = red[0] + red[1] + red[2] + red[3];
    sq = red[4] + red[5] + red[6] + red[7];
    stats[c] = s;
    stats[C + c] = sq;
  }
}

// ---------------------------------------------------------------------------
// 7. BN normalize -> d_out
// ---------------------------------------------------------------------------
__global__ __launch_bounds__(256) void bn_kernel(
    const float* __restrict__ o, const float* __restrict__ stats,
    const float* __restrict__ g, const float* __restrict__ bta,
    float* __restrict__ out)
{
  const size_t idx = (size_t)blockIdx.x * 256 + threadIdx.x;
  const float inv_n = 1.f / (float)(BB * NN);
  float4 v = ((const float4*)o)[idx];
  const int c = (int)((idx * 4 / NN) % C);
  const float mean = stats[c] * inv_n;
  const float var = stats[C + c] * inv_n - mean * mean;
  const float sc = rsqrtf(var + 1e-5f) * g[c];
  const float sh = bta[c] - mean * sc;
  v.x = v.x * sc + sh; v.y = v.y * sc + sh;
  v.z = v.z * sc + sh; v.w = v.w * sc + sh;
  ((float4*)out)[idx] = v;
}

// ---------------------------------------------------------------------------
extern "C" void kernel_launch(void* const* d_in, const int* in_sizes, int n_in,
                              void* d_out, int out_size, void* d_ws, size_t ws_size,
                              hipStream_t stream)
{
  const float* x    = (const float*)d_in[0];
  const float* hn   = (const float*)d_in[1];
  const float* w1   = (const float*)d_in[2];  const float* b1   = (const float*)d_in[3];
  const float* w2   = (const float*)d_in[4];  const float* b2   = (const float*)d_in[5];
  const float* wadj = (const float*)d_in[6];  const float* badj = (const float*)d_in[7];
  const float* tw1  = (const float*)d_in[8];  const float* tb1  = (const float*)d_in[9];
  const float* tw2  = (const float*)d_in[10]; const float* tb2  = (const float*)d_in[11];
  const float* qaw  = (const float*)d_in[12]; const float* qab  = (const float*)d_in[13];
  const float* kaw  = (const float*)d_in[14]; const float* kab  = (const float*)d_in[15];
  const float* vaw  = (const float*)d_in[16]; const float* vab  = (const float*)d_in[17];
  const float* qtw  = (const float*)d_in[18]; const float* qtb  = (const float*)d_in[19];
  const float* ktw  = (const float*)d_in[20]; const float* ktb  = (const float*)d_in[21];
  const float* vtw  = (const float*)d_in[22]; const float* vtb  = (const float*)d_in[23];
  const float* ow   = (const float*)d_in[24]; const float* obias= (const float*)d_in[25];
  const float* bng  = (const float*)d_in[26]; const float* bnb  = (const float*)d_in[27];

  // workspace plan (peak ~89.9 MB; 115.6 MB proven available in r2/r3):
  //   [a 25.69][tt 25.69][hnpad 13.79+slack][t1pad 13.79+slack][w1h 1.18][w2h 1.18]
  //   after conv2, the hnpad..w2h region is dead -> Q/K/Vt (38.5) alias it.
  char* ws = (char*)d_ws;
  const size_t TENS  = (size_t)BB * C * NN * sizeof(float);        // 25,690,112
  const size_t HTENS = (size_t)BB * NN * C * sizeof(__half);       // 12,845,056
  const size_t PADT  = (size_t)BB * PW * PW * C * sizeof(_Float16) // 13,778,944
                       + 16384;                                    // OOB-read slack
  const size_t WT    = (size_t)9 * C * C * sizeof(_Float16);       // 1,179,648
  float*    a     = (float*)(ws);
  float*    tt    = (float*)(ws + TENS);
  _Float16* hnpad = (_Float16*)(ws + 2 * TENS);
  _Float16* t1pad = (_Float16*)(ws + 2 * TENS + PADT);
  _Float16* w1h   = (_Float16*)(ws + 2 * TENS + 2 * PADT);
  _Float16* w2h   = (_Float16*)(ws + 2 * TENS + 2 * PADT + WT);
  __half*   Q     = (__half*)(ws + 2 * TENS);            // aliases hnpad (dead)
  __half*   K     = (__half*)(ws + 2 * TENS + HTENS);
  __half*   Vt    = (__half*)(ws + 2 * TENS + 2 * HTENS);
  float*    stats = (float*)(ws + 2 * TENS + 3 * HTENS); // ~89.9 MB end

  const int PIX_TILES = BB * NT;           // 1568
  const int CONV_BLKS = BB * HH * 2;       // 896
  const int FLASH_BLKS = BB * (NN / 32);   // 784

  wprep_kernel<<<9 * C * C / 256, 256, 0, stream>>>(tw1, tw2, w1h, w2h);
  padzero_kernel<<<2 * BB * PW, 256, 0, stream>>>(hnpad, t1pad);
  hnprep_kernel<<<PIX_TILES, 256, 0, stream>>>(hn, hnpad);
  attr_kernel<<<PIX_TILES, 256, 0, stream>>>(x, w1, b1, w2, b2, wadj, badj, a);
  conv_mfma_kernel<<<CONV_BLKS, 256, 0, stream>>>(hnpad, w1h, tb1, nullptr, t1pad, nullptr, 0);
  conv_mfma_kernel<<<CONV_BLKS, 256, 0, stream>>>(t1pad, w2h, tb2, a, nullptr, tt, 1);

  qkv_kernel<<<PIX_TILES, 256, 0, stream>>>(a, qaw, qab, kaw, kab, vaw, vab, Q, K, Vt, 0.5f);
  float* oattn = a;   // a dead after qkv#1
  flash2_kernel<<<FLASH_BLKS, 256, 0, stream>>>(Q, K, Vt, oattn, 0);
  qkv_kernel<<<PIX_TILES, 256, 0, stream>>>(tt, qtw, qtb, ktw, ktb, vtw, vtb, Q, K, Vt, 0.5f);
  flash2_kernel<<<FLASH_BLKS, 256, 0, stream>>>(Q, K, Vt, oattn, 1);

  float* o = tt;      // tt dead after qkv#2
  outconv_kernel<<<PIX_TILES, 256, 0, stream>>>(oattn, ow, obias, x, o);
  stats_kernel<<<C, 256, 0, stream>>>(o, stats);
  bn_kernel<<<(BB * C * NN / 4) / 256, 256, 0, stream>>>(o, stats, bng, bnb, (float*)d_out);
}

// Round 5
// 3710.243 us; speedup vs baseline: 3.8470x; 1.0050x over previous
//
#include <hip/hip_runtime.h>
#include <hip/hip_fp16.h>

#define BB 8
#define C 256
#define HH 56
#define WW 56
#define NN 3136      // HH*WW
#define RR 16
#define NT (NN/16)   // 196 pixel-tiles per image
#define PW 58        // padded spatial width/height

typedef _Float16 half8 __attribute__((ext_vector_type(8)));
typedef float floatx4 __attribute__((ext_vector_type(4)));

// ---------------------------------------------------------------------------
// 1. attr branch fused: a = adj( concat( relu(W2 relu(W1 x)), x ) )
// ---------------------------------------------------------------------------
__global__ __launch_bounds__(256) void attr_kernel(
    const float* __restrict__ x,
    const float* __restrict__ w1, const float* __restrict__ b1,
    const float* __restrict__ w2, const float* __restrict__ b2,
    const float* __restrict__ wadj, const float* __restrict__ badj,
    float* __restrict__ a_out)
{
  __shared__ float xs[C][20];
  __shared__ float a2s[C][20];
  __shared__ float a1s[RR][20];
  const int tile = blockIdx.x;
  const int b = tile / NT;
  const int p0 = (tile % NT) * 16;
  const int t = threadIdx.x;

  {
    const float* xb = x + ((size_t)b * C + t) * NN + p0;
    const float4* xb4 = (const float4*)xb;
    float* row = xs[t];
#pragma unroll
    for (int g = 0; g < 4; ++g) {
      float4 v = xb4[g];
      row[g * 4 + 0] = v.x; row[g * 4 + 1] = v.y;
      row[g * 4 + 2] = v.z; row[g * 4 + 3] = v.w;
    }
  }
  __syncthreads();

  {
    const int r = t & 15, pp = t >> 4;
    float acc = b1[r];
    const float* wr = w1 + r * C;
    for (int c = 0; c < C; ++c) acc += wr[c] * xs[c][pp];
    a1s[r][pp] = fmaxf(acc, 0.f);
  }
  __syncthreads();

  {
    const int o = t;
    float acc[16];
    const float bias = b2[o];
#pragma unroll
    for (int p = 0; p < 16; ++p) acc[p] = bias;
    const float* wr = w2 + o * RR;
    for (int k = 0; k < RR; ++k) {
      const float w = wr[k];
#pragma unroll
      for (int p = 0; p < 16; ++p) acc[p] += w * a1s[k][p];
    }
    float* row = a2s[o];
#pragma unroll
    for (int p = 0; p < 16; ++p) row[p] = fmaxf(acc[p], 0.f);
  }
  __syncthreads();

  {
    const int o = t;
    float acc[16];
    const float bias = badj[o];
#pragma unroll
    for (int p = 0; p < 16; ++p) acc[p] = bias;
    const float* wr = wadj + (size_t)o * (2 * C);
    for (int k = 0; k < C; ++k) {
      const float w = wr[k];
      const float4* ar = (const float4*)a2s[k];
#pragma unroll
      for (int g = 0; g < 4; ++g) {
        float4 v = ar[g];
        acc[g * 4 + 0] += w * v.x; acc[g * 4 + 1] += w * v.y;
        acc[g * 4 + 2] += w * v.z; acc[g * 4 + 3] += w * v.w;
      }
    }
    for (int k = 0; k < C; ++k) {
      const float w = wr[C + k];
      const float4* xr = (const float4*)xs[k];
#pragma unroll
      for (int g = 0; g < 4; ++g) {
        float4 v = xr[g];
        acc[g * 4 + 0] += w * v.x; acc[g * 4 + 1] += w * v.y;
        acc[g * 4 + 2] += w * v.z; acc[g * 4 + 3] += w * v.w;
      }
    }
    float* op = a_out + ((size_t)b * C + o) * NN + p0;
    float4* op4 = (float4*)op;
#pragma unroll
    for (int g = 0; g < 4; ++g)
      op4[g] = make_float4(acc[g * 4 + 0], acc[g * 4 + 1], acc[g * 4 + 2], acc[g * 4 + 3]);
  }
}

// ---------------------------------------------------------------------------
// 2a. weight prep: w1h[tap][o][c] = tw1[o][c][tap] (fp16)
//     w2h[tap][o][c] = tw2[o][c][8-tap]  (convT spatial flip folded in)
// ---------------------------------------------------------------------------
__global__ __launch_bounds__(256) void wprep_kernel(
    const float* __restrict__ tw1, const float* __restrict__ tw2,
    _Float16* __restrict__ w1h, _Float16* __restrict__ w2h)
{
  const int i = blockIdx.x * 256 + threadIdx.x;   // over 9*256*256
  const int tap = i >> 16;
  const int rem = i & 65535;
  const int o = rem >> 8;
  const int c = rem & 255;
  w1h[i] = (_Float16)tw1[((size_t)o * C + c) * 9 + tap];
  w2h[i] = (_Float16)tw2[((size_t)o * C + c) * 9 + (8 - tap)];
}

// ---------------------------------------------------------------------------
// 2b. zero the pad border of both padded-NHWC fp16 buffers
// ---------------------------------------------------------------------------
__global__ __launch_bounds__(256) void padzero_kernel(
    _Float16* __restrict__ buf1, _Float16* __restrict__ buf2)
{
  const int bid = blockIdx.x;                 // 2 * BB * PW
  _Float16* buf = (bid < BB * PW) ? buf1 : buf2;
  const int rb = bid % (BB * PW);
  const int b = rb / PW, r = rb % PW;
  _Float16* row = buf + ((size_t)b * PW + r) * PW * C;
  const float4 z = make_float4(0.f, 0.f, 0.f, 0.f);
  if (r == 0 || r == PW - 1) {
    for (int i = threadIdx.x; i < PW * C / 8; i += 256) ((float4*)row)[i] = z;
  } else {
    const int i = threadIdx.x;
    if (i < 32) ((float4*)row)[i] = z;                       // col 0
    else if (i < 64) ((float4*)(row + (PW - 1) * C))[i - 32] = z;  // col 57
  }
}

// ---------------------------------------------------------------------------
// 2c. hn (fp32 NCHW) -> hnpad (fp16 padded NHWC) interior, via LDS transpose
// ---------------------------------------------------------------------------
__global__ __launch_bounds__(256) void hnprep_kernel(
    const float* __restrict__ hn, _Float16* __restrict__ hnpad)
{
  __shared__ float xs[C][17];
  const int tile = blockIdx.x;
  const int b = tile / NT;
  const int p0 = (tile % NT) * 16;
  const int t = threadIdx.x;
  {
    const float4* sb = (const float4*)(hn + ((size_t)b * C + t) * NN + p0);
    float* row = xs[t];
#pragma unroll
    for (int g = 0; g < 4; ++g) {
      float4 v = sb[g];
      row[g * 4 + 0] = v.x; row[g * 4 + 1] = v.y;
      row[g * 4 + 2] = v.z; row[g * 4 + 3] = v.w;
    }
  }
  __syncthreads();
  const int p = t >> 4, c0 = (t & 15) * 16;
  const int pg = p0 + p;
  const int h = pg / WW, w = pg % WW;
  __align__(16) _Float16 tmp[16];
#pragma unroll
  for (int j = 0; j < 16; ++j) tmp[j] = (_Float16)xs[c0 + j][p];
  _Float16* dst = hnpad + (((size_t)b * PW + h + 1) * PW + w + 1) * C + c0;
  ((uint4*)dst)[0] = ((uint4*)tmp)[0];
  ((uint4*)dst)[1] = ((uint4*)tmp)[1];
}

// ---------------------------------------------------------------------------
// 2d. conv3x3 as 9-tap MFMA GEMM.  XCD-swizzled: b = bid & 7 so each XCD
//     (round-robin bid%8) touches one batch -> input slice stays in its L2.
// ---------------------------------------------------------------------------
__global__ __launch_bounds__(256) void conv_mfma_kernel(
    const _Float16* __restrict__ inpad, const _Float16* __restrict__ wh,
    const float* __restrict__ bias, const float* __restrict__ amul,
    _Float16* __restrict__ out_h, float* __restrict__ out_f, int mode)
{
  const int bid = blockIdx.x;          // BB*56*2
  const int b = bid & 7;               // XCD-aligned batch
  const int rest = bid >> 3;           // 0..111
  const int ohalf = rest & 1;
  const int h = rest >> 1;
  const int t = threadIdx.x;
  const int wave = t >> 6, lane = t & 63;
  const int col = lane & 15, quad = lane >> 4;
  const int o_base = ohalf * 128 + wave * 32;

  floatx4 acc[2][4];
#pragma unroll
  for (int mt = 0; mt < 2; ++mt)
#pragma unroll
    for (int nt = 0; nt < 4; ++nt) acc[mt][nt] = (floatx4){0.f, 0.f, 0.f, 0.f};

  const _Float16* inb = inpad + (size_t)b * PW * PW * C;

  for (int tap = 0; tap < 9; ++tap) {
    const int dy = tap / 3;
    const int dx = tap - dy * 3;
    const _Float16* wtap = wh + (size_t)tap * C * C + quad * 8;
    const _Float16* inrow = inb + ((size_t)(h + dy) * PW + dx + col) * C + quad * 8;
    for (int kc = 0; kc < 8; ++kc) {
      const int c0 = kc * 32;
      const half8 A0 = *(const half8*)(wtap + (size_t)(o_base + col) * C + c0);
      const half8 A1 = *(const half8*)(wtap + (size_t)(o_base + 16 + col) * C + c0);
#pragma unroll
      for (int nt = 0; nt < 4; ++nt) {
        const half8 Bv = *(const half8*)(inrow + (size_t)(nt * 16) * C + c0);
        acc[0][nt] = __builtin_amdgcn_mfma_f32_16x16x32_f16(A0, Bv, acc[0][nt], 0, 0, 0);
        acc[1][nt] = __builtin_amdgcn_mfma_f32_16x16x32_f16(A1, Bv, acc[1][nt], 0, 0, 0);
      }
    }
  }

  // epilogue: C-frag row (o) = quad*4+r, col (pixel) = nt*16+col
#pragma unroll
  for (int mt = 0; mt < 2; ++mt) {
    const int o = o_base + mt * 16 + quad * 4;
    const float* bp = bias + o;
    const float b0 = bp[0], b1_ = bp[1], b2_ = bp[2], b3 = bp[3];
    if (mode == 0) {
#pragma unroll
      for (int nt = 0; nt < 4; ++nt) {
        const int wpx = nt * 16 + col;
        if (wpx < WW) {
          __align__(8) _Float16 hv[4];
          hv[0] = (_Float16)fmaxf(acc[mt][nt][0] + b0, 0.f);
          hv[1] = (_Float16)fmaxf(acc[mt][nt][1] + b1_, 0.f);
          hv[2] = (_Float16)fmaxf(acc[mt][nt][2] + b2_, 0.f);
          hv[3] = (_Float16)fmaxf(acc[mt][nt][3] + b3, 0.f);
          _Float16* dst = out_h + (((size_t)b * PW + h + 1) * PW + wpx + 1) * C + o;
          *(uint2*)dst = *(uint2*)hv;
        }
      }
    } else {
#pragma unroll
      for (int nt = 0; nt < 4; ++nt) {
        const int wpx = nt * 16 + col;
        if (wpx < WW) {
          const int p = h * WW + wpx;
          const float bb[4] = {b0, b1_, b2_, b3};
#pragma unroll
          for (int r = 0; r < 4; ++r) {
            const size_t idx = ((size_t)(b * C + o + r)) * NN + p;
            out_f[idx] = (acc[mt][nt][r] + bb[r]) * amul[idx];
          }
        }
      }
    }
  }
}

// ---------------------------------------------------------------------------
// 3. fused Q/K/V linears: src [B][C][N] -> Q,K fp16 [B][N][C], Vt fp16 [B][C][N]
// ---------------------------------------------------------------------------
__global__ __launch_bounds__(256) void qkv_kernel(
    const float* __restrict__ src,
    const float* __restrict__ wq, const float* __restrict__ bq,
    const float* __restrict__ wk, const float* __restrict__ bk,
    const float* __restrict__ wv, const float* __restrict__ bv,
    __half* __restrict__ Q, __half* __restrict__ K, __half* __restrict__ Vt,
    float vscale)
{
  __shared__ float ss[C][20];
  const int tile = blockIdx.x;
  const int b = tile / NT;
  const int p0 = (tile % NT) * 16;
  const int t = threadIdx.x;
  {
    const float4* sb = (const float4*)(src + ((size_t)b * C + t) * NN + p0);
    float* row = ss[t];
#pragma unroll
    for (int g = 0; g < 4; ++g) {
      float4 v = sb[g];
      row[g * 4 + 0] = v.x; row[g * 4 + 1] = v.y;
      row[g * 4 + 2] = v.z; row[g * 4 + 3] = v.w;
    }
  }
  __syncthreads();

  const int o = t;
  float aq[16], ak[16], av[16];
  {
    const float q0 = bq[o], k0 = bk[o], v0 = bv[o];
#pragma unroll
    for (int p = 0; p < 16; ++p) { aq[p] = q0; ak[p] = k0; av[p] = v0; }
  }
  const float* wqr = wq + o * C;
  const float* wkr = wk + o * C;
  const float* wvr = wv + o * C;
  for (int k = 0; k < C; ++k) {
    const float fq = wqr[k], fk = wkr[k], fv = wvr[k];
    const float4* sr = (const float4*)ss[k];
#pragma unroll
    for (int g = 0; g < 4; ++g) {
      float4 s = sr[g];
      aq[g * 4 + 0] += fq * s.x; aq[g * 4 + 1] += fq * s.y; aq[g * 4 + 2] += fq * s.z; aq[g * 4 + 3] += fq * s.w;
      ak[g * 4 + 0] += fk * s.x; ak[g * 4 + 1] += fk * s.y; ak[g * 4 + 2] += fk * s.z; ak[g * 4 + 3] += fk * s.w;
      av[g * 4 + 0] += fv * s.x; av[g * 4 + 1] += fv * s.y; av[g * 4 + 2] += fv * s.z; av[g * 4 + 3] += fv * s.w;
    }
  }
#pragma unroll
  for (int p = 0; p < 16; ++p) {
    const size_t base = ((size_t)(b * NN) + p0 + p) * C + o;
    Q[base] = __float2half(aq[p]);
    K[base] = __float2half(ak[p]);
  }
  __align__(16) __half hv[16];
#pragma unroll
  for (int p = 0; p < 16; ++p) hv[p] = __float2half(av[p] * vscale);
  __half* vtp = Vt + ((size_t)(b * C) + o) * NN + p0;
  ((uint4*)vtp)[0] = ((uint4*)hv)[0];
  ((uint4*)vtp)[1] = ((uint4*)hv)[1];
}

// ---------------------------------------------------------------------------
// 4. MFMA flash attention (16x16x32 f16).
//    XCD-swizzled: b = bid & 7 -> XCD x (bid%8 round-robin) only touches
//    batch x, so K_b+V_b (3.2 MB) stays resident in that XCD's 4 MiB L2
//    instead of thrashing to Infinity Cache (r4: 160 MB FETCH, ~6 TB/s wall).
// ---------------------------------------------------------------------------
__global__ __launch_bounds__(256) void flash2_kernel(
    const __half* __restrict__ Qg, const __half* __restrict__ Kg,
    const __half* __restrict__ Vtg, float* __restrict__ O, int accumulate)
{
  __shared__ __half Pbuf[4][16][68];
  __shared__ float Obuf[2][16][258];
  __shared__ float mlb[2][2][16];

  const int bid = blockIdx.x;
  const int b = bid & 7;               // XCD-aligned batch
  const int q0 = (bid >> 3) * 32;      // 0..97 q-tiles
  const int t = threadIdx.x;
  const int w = t >> 6;
  const int lane = t & 63;
  const int col = lane & 15;
  const int quad = lane >> 4;
  const int pairid = w & 1;
  const int role = w >> 1;

  const _Float16* Qp = (const _Float16*)Qg +
      ((size_t)(b * NN) + q0 + pairid * 16 + col) * C + quad * 8;
  half8 Qf[8];
#pragma unroll
  for (int s = 0; s < 8; ++s) Qf[s] = *(const half8*)(Qp + s * 32);

  floatx4 Ov[16];
#pragma unroll
  for (int n = 0; n < 16; ++n) Ov[n] = (floatx4){0.f, 0.f, 0.f, 0.f};
  float m[4] = {-1e30f, -1e30f, -1e30f, -1e30f};
  float l[4] = {0.f, 0.f, 0.f, 0.f};

  const _Float16* Kb = (const _Float16*)Kg + (size_t)(b * NN) * C;
  const _Float16* Vb = (const _Float16*)Vtg + (size_t)(b * C) * NN;

  for (int kb = role; kb < 49; kb += 2) {
    const int key0 = kb * 64;
    floatx4 Sv[4];
#pragma unroll
    for (int nt = 0; nt < 4; ++nt) {
      floatx4 acc = (floatx4){0.f, 0.f, 0.f, 0.f};
      const _Float16* kp = Kb + (size_t)(key0 + nt * 16 + col) * C + quad * 8;
#pragma unroll
      for (int s = 0; s < 8; ++s) {
        half8 bf = *(const half8*)(kp + s * 32);
        acc = __builtin_amdgcn_mfma_f32_16x16x32_f16(Qf[s], bf, acc, 0, 0, 0);
      }
      Sv[nt] = acc * 0.0625f;
    }
    float f[4];
#pragma unroll
    for (int r = 0; r < 4; ++r) {
      float v = fmaxf(fmaxf(Sv[0][r], Sv[1][r]), fmaxf(Sv[2][r], Sv[3][r]));
      v = fmaxf(v, __shfl_xor(v, 1));
      v = fmaxf(v, __shfl_xor(v, 2));
      v = fmaxf(v, __shfl_xor(v, 4));
      v = fmaxf(v, __shfl_xor(v, 8));
      const float mn = fmaxf(m[r], v);
      f[r] = __expf(m[r] - mn);
      m[r] = mn;
    }
    float rowsum[4] = {0.f, 0.f, 0.f, 0.f};
#pragma unroll
    for (int nt = 0; nt < 4; ++nt) {
#pragma unroll
      for (int r = 0; r < 4; ++r) {
        const float p = __expf(Sv[nt][r] - m[r]);
        Sv[nt][r] = p;
        rowsum[r] += p;
      }
    }
#pragma unroll
    for (int r = 0; r < 4; ++r) {
      float s = rowsum[r];
      s += __shfl_xor(s, 1);
      s += __shfl_xor(s, 2);
      s += __shfl_xor(s, 4);
      s += __shfl_xor(s, 8);
      l[r] = l[r] * f[r] + s;
    }
#pragma unroll
    for (int nt = 0; nt < 4; ++nt)
#pragma unroll
      for (int r = 0; r < 4; ++r)
        Pbuf[w][quad * 4 + r][nt * 16 + col] = __float2half(Sv[nt][r]);
    const floatx4 fv = {f[0], f[1], f[2], f[3]};
#pragma unroll
    for (int n = 0; n < 16; ++n) Ov[n] *= fv;
    const half8 pa0 = *(const half8*)&Pbuf[w][col][quad * 8];
    const half8 pa1 = *(const half8*)&Pbuf[w][col][32 + quad * 8];
#pragma unroll
    for (int nt2 = 0; nt2 < 16; ++nt2) {
      const _Float16* vp = Vb + (size_t)(nt2 * 16 + col) * NN + key0 + quad * 8;
      const half8 bv0 = *(const half8*)vp;
      const half8 bv1 = *(const half8*)(vp + 32);
      Ov[nt2] = __builtin_amdgcn_mfma_f32_16x16x32_f16(pa0, bv0, Ov[nt2], 0, 0, 0);
      Ov[nt2] = __builtin_amdgcn_mfma_f32_16x16x32_f16(pa1, bv1, Ov[nt2], 0, 0, 0);
    }
  }

  if (role == 1) {
#pragma unroll
    for (int nt2 = 0; nt2 < 16; ++nt2)
#pragma unroll
      for (int r = 0; r < 4; ++r)
        Obuf[pairid][quad * 4 + r][nt2 * 16 + col] = Ov[nt2][r];
    if (col == 0) {
#pragma unroll
      for (int r = 0; r < 4; ++r) {
        mlb[pairid][0][quad * 4 + r] = m[r];
        mlb[pairid][1][quad * 4 + r] = l[r];
      }
    }
  }
  __syncthreads();
  if (role == 0) {
    float f1[4], f2[4], inv[4];
#pragma unroll
    for (int r = 0; r < 4; ++r) {
      const float m2 = mlb[pairid][0][quad * 4 + r];
      const float l2 = mlb[pairid][1][quad * 4 + r];
      const float M = fmaxf(m[r], m2);
      f1[r] = __expf(m[r] - M);
      f2[r] = __expf(m2 - M);
      inv[r] = 1.f / (l[r] * f1[r] + l2 * f2[r]);
    }
#pragma unroll
    for (int nt2 = 0; nt2 < 16; ++nt2) {
#pragma unroll
      for (int r = 0; r < 4; ++r) {
        const float val =
            (Ov[nt2][r] * f1[r] +
             Obuf[pairid][quad * 4 + r][nt2 * 16 + col] * f2[r]) * inv[r];
        float* dst = O + ((size_t)(b * NN) + q0 + pairid * 16 + quad * 4 + r) * C +
                     nt2 * 16 + col;
        if (accumulate) *dst += val; else *dst = val;
      }
    }
  }
}

// ---------------------------------------------------------------------------
// 5. out 1x1 conv + residual
// ---------------------------------------------------------------------------
__global__ __launch_bounds__(256) void outconv_kernel(
    const float* __restrict__ oattn, const float* __restrict__ ow,
    const float* __restrict__ ob, const float* __restrict__ x,
    float* __restrict__ o)
{
  __shared__ float os[16][260];
  const int tile = blockIdx.x;
  const int b = tile / NT;
  const int p0 = (tile % NT) * 16;
  const int t = threadIdx.x;
  {
    const int p = t >> 4, c0 = (t & 15) * 16;
    const float4* src = (const float4*)(oattn + ((size_t)(b * NN) + p0 + p) * C + c0);
    float4* dst = (float4*)(os[p] + c0);
#pragma unroll
    for (int g = 0; g < 4; ++g) dst[g] = src[g];
  }
  __syncthreads();

  const int oc = t;
  float acc[16];
  {
    const float bias = ob[oc];
#pragma unroll
    for (int p = 0; p < 16; ++p) acc[p] = bias;
  }
  const float4* wr = (const float4*)(ow + (size_t)oc * C);
  for (int k4 = 0; k4 < 64; ++k4) {
    const float4 w = wr[k4];
#pragma unroll
    for (int p = 0; p < 16; ++p) {
      const float4 v = *(const float4*)(os[p] + k4 * 4);
      acc[p] += w.x * v.x + w.y * v.y + w.z * v.z + w.w * v.w;
    }
  }
  const float4* xp4 = (const float4*)(x + ((size_t)b * C + oc) * NN + p0);
  float4* op4 = (float4*)(o + ((size_t)b * C + oc) * NN + p0);
#pragma unroll
  for (int g = 0; g < 4; ++g) {
    const float4 xv = xp4[g];
    op4[g] = make_float4(acc[g * 4 + 0] + xv.x, acc[g * 4 + 1] + xv.y,
                         acc[g * 4 + 2] + xv.z, acc[g * 4 + 3] + xv.w);
  }
}

// ---------------------------------------------------------------------------
// 6. BN stats
// ---------------------------------------------------------------------------
__global__ __launch_bounds__(256) void stats_kernel(
    const float* __restrict__ o, float* __restrict__ stats)
{
  const int c = blockIdx.x, t = threadIdx.x;
  float s = 0.f, sq = 0.f;
  for (int b = 0; b < BB; ++b) {
    const float* p = o + ((size_t)b * C + c) * NN;
    for (int idx = t; idx < NN; idx += 256) {
      const float v = p[idx];
      s += v; sq += v * v;
    }
  }
#pragma unroll
  for (int off = 32; off >= 1; off >>= 1) {
    s += __shfl_xor(s, off);
    sq += __shfl_xor(sq, off);
  }
  __shared__ float red[8];
  const int wv = t >> 6;
  if ((t & 63) == 0) { red[wv] = s; red[4 + wv] = sq; }
  __syncthreads();
  if (t == 0) {
    s = red[0] + red[1] + red[2] + red[3];
    sq = red[4] + red[5] + red[6] + red[7];
    stats[c] = s;
    stats[C + c] = sq;
  }
}

// ---------------------------------------------------------------------------
// 7. BN normalize -> d_out
// ---------------------------------------------------------------------------
__global__ __launch_bounds__(256) void bn_kernel(
    const float* __restrict__ o, const float* __restrict__ stats,
    const float* __restrict__ g, const float* __restrict__ bta,
    float* __restrict__ out)
{
  const size_t idx = (size_t)blockIdx.x * 256 + threadIdx.x;
  const float inv_n = 1.f / (float)(BB * NN);
  float4 v = ((const float4*)o)[idx];
  const int c = (int)((idx * 4 / NN) % C);
  const float mean = stats[c] * inv_n;
  const float var = stats[C + c] * inv_n - mean * mean;
  const float sc = rsqrtf(var + 1e-5f) * g[c];
  const float sh = bta[c] - mean * sc;
  v.x = v.x * sc + sh; v.y = v.y * sc + sh;
  v.z = v.z * sc + sh; v.w = v.w * sc + sh;
  ((float4*)out)[idx] = v;
}

// ---------------------------------------------------------------------------
extern "C" void kernel_launch(void* const* d_in, const int* in_sizes, int n_in,
                              void* d_out, int out_size, void* d_ws, size_t ws_size,
                              hipStream_t stream)
{
  const float* x    = (const float*)d_in[0];
  const float* hn   = (const float*)d_in[1];
  const float* w1   = (const float*)d_in[2];  const float* b1   = (const float*)d_in[3];
  const float* w2   = (const float*)d_in[4];  const float* b2   = (const float*)d_in[5];
  const float* wadj = (const float*)d_in[6];  const float* badj = (const float*)d_in[7];
  const float* tw1  = (const float*)d_in[8];  const float* tb1  = (const float*)d_in[9];
  const float* tw2  = (const float*)d_in[10]; const float* tb2  = (const float*)d_in[11];
  const float* qaw  = (const float*)d_in[12]; const float* qab  = (const float*)d_in[13];
  const float* kaw  = (const float*)d_in[14]; const float* kab  = (const float*)d_in[15];
  const float* vaw  = (const float*)d_in[16]; const float* vab  = (const float*)d_in[17];
  const float* qtw  = (const float*)d_in[18]; const float* qtb  = (const float*)d_in[19];
  const float* ktw  = (const float*)d_in[20]; const float* ktb  = (const float*)d_in[21];
  const float* vtw  = (const float*)d_in[22]; const float* vtb  = (const float*)d_in[23];
  const float* ow   = (const float*)d_in[24]; const float* obias= (const float*)d_in[25];
  const float* bng  = (const float*)d_in[26]; const float* bnb  = (const float*)d_in[27];

  // workspace plan (peak ~89.9 MB):
  //   [a 25.69][tt 25.69][hnpad 13.79+slack][t1pad 13.79+slack][w1h 1.18][w2h 1.18]
  //   after conv2, the hnpad..w2h region is dead -> Q/K/Vt (38.5) alias it.
  char* ws = (char*)d_ws;
  const size_t TENS  = (size_t)BB * C * NN * sizeof(float);        // 25,690,112
  const size_t HTENS = (size_t)BB * NN * C * sizeof(__half);       // 12,845,056
  const size_t PADT  = (size_t)BB * PW * PW * C * sizeof(_Float16) // 13,778,944
                       + 16384;                                    // OOB-read slack
  const size_t WT    = (size_t)9 * C * C * sizeof(_Float16);       // 1,179,648
  float*    a     = (float*)(ws);
  float*    tt    = (float*)(ws + TENS);
  _Float16* hnpad = (_Float16*)(ws + 2 * TENS);
  _Float16* t1pad = (_Float16*)(ws + 2 * TENS + PADT);
  _Float16* w1h   = (_Float16*)(ws + 2 * TENS + 2 * PADT);
  _Float16* w2h   = (_Float16*)(ws + 2 * TENS + 2 * PADT + WT);
  __half*   Q     = (__half*)(ws + 2 * TENS);            // aliases hnpad (dead)
  __half*   K     = (__half*)(ws + 2 * TENS + HTENS);
  __half*   Vt    = (__half*)(ws + 2 * TENS + 2 * HTENS);
  float*    stats = (float*)(ws + 2 * TENS + 3 * HTENS); // ~89.9 MB end

  const int PIX_TILES = BB * NT;           // 1568
  const int CONV_BLKS = BB * HH * 2;       // 896
  const int FLASH_BLKS = BB * (NN / 32);   // 784

  wprep_kernel<<<9 * C * C / 256, 256, 0, stream>>>(tw1, tw2, w1h, w2h);
  padzero_kernel<<<2 * BB * PW, 256, 0, stream>>>(hnpad, t1pad);
  hnprep_kernel<<<PIX_TILES, 256, 0, stream>>>(hn, hnpad);
  attr_kernel<<<PIX_TILES, 256, 0, stream>>>(x, w1, b1, w2, b2, wadj, badj, a);
  conv_mfma_kernel<<<CONV_BLKS, 256, 0, stream>>>(hnpad, w1h, tb1, nullptr, t1pad, nullptr, 0);
  conv_mfma_kernel<<<CONV_BLKS, 256, 0, stream>>>(t1pad, w2h, tb2, a, nullptr, tt, 1);

  qkv_kernel<<<PIX_TILES, 256, 0, stream>>>(a, qaw, qab, kaw, kab, vaw, vab, Q, K, Vt, 0.5f);
  float* oattn = a;   // a dead after qkv#1
  flash2_kernel<<<FLASH_BLKS, 256, 0, stream>>>(Q, K, Vt, oattn, 0);
  qkv_kernel<<<PIX_TILES, 256, 0, stream>>>(tt, qtw, qtb, ktw, ktb, vtw, vtb, Q, K, Vt, 0.5f);
  flash2_kernel<<<FLASH_BLKS, 256, 0, stream>>>(Q, K, Vt, oattn, 1);

  float* o = tt;      // tt dead after qkv#2
  outconv_kernel<<<PIX_TILES, 256, 0, stream>>>(oattn, ow, obias, x, o);
  stats_kernel<<<C, 256, 0, stream>>>(o, stats);
  bn_kernel<<<(BB * C * NN / 4) / 256, 256, 0, stream>>>(o, stats, bng, bnb, (float*)d_out);
}

// Round 6
// 3231.141 us; speedup vs baseline: 4.4174x; 1.1483x over previous
//
#include <hip/hip_runtime.h>
#include <hip/hip_fp16.h>

#define BB 8
#define C 256
#define HH 56
#define WW 56
#define NN 3136      // HH*WW
#define RR 16
#define NT (NN/16)   // 196 pixel-tiles per image
#define PW 58        // padded spatial width/height

typedef _Float16 half8 __attribute__((ext_vector_type(8)));
typedef _Float16 half4v __attribute__((ext_vector_type(4)));
typedef float floatx4 __attribute__((ext_vector_type(4)));

// ---------------------------------------------------------------------------
// 1. attr branch fused: a = adj( concat( relu(W2 relu(W1 x)), x ) )
// ---------------------------------------------------------------------------
__global__ __launch_bounds__(256) void attr_kernel(
    const float* __restrict__ x,
    const float* __restrict__ w1, const float* __restrict__ b1,
    const float* __restrict__ w2, const float* __restrict__ b2,
    const float* __restrict__ wadj, const float* __restrict__ badj,
    float* __restrict__ a_out)
{
  __shared__ float xs[C][20];
  __shared__ float a2s[C][20];
  __shared__ float a1s[RR][20];
  const int tile = blockIdx.x;
  const int b = tile / NT;
  const int p0 = (tile % NT) * 16;
  const int t = threadIdx.x;

  {
    const float* xb = x + ((size_t)b * C + t) * NN + p0;
    const float4* xb4 = (const float4*)xb;
    float* row = xs[t];
#pragma unroll
    for (int g = 0; g < 4; ++g) {
      float4 v = xb4[g];
      row[g * 4 + 0] = v.x; row[g * 4 + 1] = v.y;
      row[g * 4 + 2] = v.z; row[g * 4 + 3] = v.w;
    }
  }
  __syncthreads();

  {
    const int r = t & 15, pp = t >> 4;
    float acc = b1[r];
    const float* wr = w1 + r * C;
    for (int c = 0; c < C; ++c) acc += wr[c] * xs[c][pp];
    a1s[r][pp] = fmaxf(acc, 0.f);
  }
  __syncthreads();

  {
    const int o = t;
    float acc[16];
    const float bias = b2[o];
#pragma unroll
    for (int p = 0; p < 16; ++p) acc[p] = bias;
    const float* wr = w2 + o * RR;
    for (int k = 0; k < RR; ++k) {
      const float w = wr[k];
#pragma unroll
      for (int p = 0; p < 16; ++p) acc[p] += w * a1s[k][p];
    }
    float* row = a2s[o];
#pragma unroll
    for (int p = 0; p < 16; ++p) row[p] = fmaxf(acc[p], 0.f);
  }
  __syncthreads();

  {
    const int o = t;
    float acc[16];
    const float bias = badj[o];
#pragma unroll
    for (int p = 0; p < 16; ++p) acc[p] = bias;
    const float* wr = wadj + (size_t)o * (2 * C);
    for (int k = 0; k < C; ++k) {
      const float w = wr[k];
      const float4* ar = (const float4*)a2s[k];
#pragma unroll
      for (int g = 0; g < 4; ++g) {
        float4 v = ar[g];
        acc[g * 4 + 0] += w * v.x; acc[g * 4 + 1] += w * v.y;
        acc[g * 4 + 2] += w * v.z; acc[g * 4 + 3] += w * v.w;
      }
    }
    for (int k = 0; k < C; ++k) {
      const float w = wr[C + k];
      const float4* xr = (const float4*)xs[k];
#pragma unroll
      for (int g = 0; g < 4; ++g) {
        float4 v = xr[g];
        acc[g * 4 + 0] += w * v.x; acc[g * 4 + 1] += w * v.y;
        acc[g * 4 + 2] += w * v.z; acc[g * 4 + 3] += w * v.w;
      }
    }
    float* op = a_out + ((size_t)b * C + o) * NN + p0;
    float4* op4 = (float4*)op;
#pragma unroll
    for (int g = 0; g < 4; ++g)
      op4[g] = make_float4(acc[g * 4 + 0], acc[g * 4 + 1], acc[g * 4 + 2], acc[g * 4 + 3]);
  }
}

// ---------------------------------------------------------------------------
// 2a. weight prep: w1h[tap][o][c] = tw1[o][c][tap] (fp16)
//     w2h[tap][o][c] = tw2[o][c][8-tap]  (convT spatial flip folded in)
// ---------------------------------------------------------------------------
__global__ __launch_bounds__(256) void wprep_kernel(
    const float* __restrict__ tw1, const float* __restrict__ tw2,
    _Float16* __restrict__ w1h, _Float16* __restrict__ w2h)
{
  const int i = blockIdx.x * 256 + threadIdx.x;   // over 9*256*256
  const int tap = i >> 16;
  const int rem = i & 65535;
  const int o = rem >> 8;
  const int c = rem & 255;
  w1h[i] = (_Float16)tw1[((size_t)o * C + c) * 9 + tap];
  w2h[i] = (_Float16)tw2[((size_t)o * C + c) * 9 + (8 - tap)];
}

// ---------------------------------------------------------------------------
// 2b. zero the pad border of both padded-NHWC fp16 buffers
// ---------------------------------------------------------------------------
__global__ __launch_bounds__(256) void padzero_kernel(
    _Float16* __restrict__ buf1, _Float16* __restrict__ buf2)
{
  const int bid = blockIdx.x;                 // 2 * BB * PW
  _Float16* buf = (bid < BB * PW) ? buf1 : buf2;
  const int rb = bid % (BB * PW);
  const int b = rb / PW, r = rb % PW;
  _Float16* row = buf + ((size_t)b * PW + r) * PW * C;
  const float4 z = make_float4(0.f, 0.f, 0.f, 0.f);
  if (r == 0 || r == PW - 1) {
    for (int i = threadIdx.x; i < PW * C / 8; i += 256) ((float4*)row)[i] = z;
  } else {
    const int i = threadIdx.x;
    if (i < 32) ((float4*)row)[i] = z;                       // col 0
    else if (i < 64) ((float4*)(row + (PW - 1) * C))[i - 32] = z;  // col 57
  }
}

// ---------------------------------------------------------------------------
// 2c. hn (fp32 NCHW) -> hnpad (fp16 padded NHWC) interior, via LDS transpose
// ---------------------------------------------------------------------------
__global__ __launch_bounds__(256) void hnprep_kernel(
    const float* __restrict__ hn, _Float16* __restrict__ hnpad)
{
  __shared__ float xs[C][17];
  const int tile = blockIdx.x;
  const int b = tile / NT;
  const int p0 = (tile % NT) * 16;
  const int t = threadIdx.x;
  {
    const float4* sb = (const float4*)(hn + ((size_t)b * C + t) * NN + p0);
    float* row = xs[t];
#pragma unroll
    for (int g = 0; g < 4; ++g) {
      float4 v = sb[g];
      row[g * 4 + 0] = v.x; row[g * 4 + 1] = v.y;
      row[g * 4 + 2] = v.z; row[g * 4 + 3] = v.w;
    }
  }
  __syncthreads();
  const int p = t >> 4, c0 = (t & 15) * 16;
  const int pg = p0 + p;
  const int h = pg / WW, w = pg % WW;
  __align__(16) _Float16 tmp[16];
#pragma unroll
  for (int j = 0; j < 16; ++j) tmp[j] = (_Float16)xs[c0 + j][p];
  _Float16* dst = hnpad + (((size_t)b * PW + h + 1) * PW + w + 1) * C + c0;
  ((uint4*)dst)[0] = ((uint4*)tmp)[0];
  ((uint4*)dst)[1] = ((uint4*)tmp)[1];
}

// ---------------------------------------------------------------------------
// 2d. conv3x3 as 9-tap MFMA GEMM.  XCD-swizzled (b = bid & 7).
// ---------------------------------------------------------------------------
__global__ __launch_bounds__(256) void conv_mfma_kernel(
    const _Float16* __restrict__ inpad, const _Float16* __restrict__ wh,
    const float* __restrict__ bias, const float* __restrict__ amul,
    _Float16* __restrict__ out_h, float* __restrict__ out_f, int mode)
{
  const int bid = blockIdx.x;          // BB*56*2
  const int b = bid & 7;               // XCD-aligned batch
  const int rest = bid >> 3;           // 0..111
  const int ohalf = rest & 1;
  const int h = rest >> 1;
  const int t = threadIdx.x;
  const int wave = t >> 6, lane = t & 63;
  const int col = lane & 15, quad = lane >> 4;
  const int o_base = ohalf * 128 + wave * 32;

  floatx4 acc[2][4];
#pragma unroll
  for (int mt = 0; mt < 2; ++mt)
#pragma unroll
    for (int nt = 0; nt < 4; ++nt) acc[mt][nt] = (floatx4){0.f, 0.f, 0.f, 0.f};

  const _Float16* inb = inpad + (size_t)b * PW * PW * C;

  for (int tap = 0; tap < 9; ++tap) {
    const int dy = tap / 3;
    const int dx = tap - dy * 3;
    const _Float16* wtap = wh + (size_t)tap * C * C + quad * 8;
    const _Float16* inrow = inb + ((size_t)(h + dy) * PW + dx + col) * C + quad * 8;
    for (int kc = 0; kc < 8; ++kc) {
      const int c0 = kc * 32;
      const half8 A0 = *(const half8*)(wtap + (size_t)(o_base + col) * C + c0);
      const half8 A1 = *(const half8*)(wtap + (size_t)(o_base + 16 + col) * C + c0);
#pragma unroll
      for (int nt = 0; nt < 4; ++nt) {
        const half8 Bv = *(const half8*)(inrow + (size_t)(nt * 16) * C + c0);
        acc[0][nt] = __builtin_amdgcn_mfma_f32_16x16x32_f16(A0, Bv, acc[0][nt], 0, 0, 0);
        acc[1][nt] = __builtin_amdgcn_mfma_f32_16x16x32_f16(A1, Bv, acc[1][nt], 0, 0, 0);
      }
    }
  }

#pragma unroll
  for (int mt = 0; mt < 2; ++mt) {
    const int o = o_base + mt * 16 + quad * 4;
    const float* bp = bias + o;
    const float b0 = bp[0], b1_ = bp[1], b2_ = bp[2], b3 = bp[3];
    if (mode == 0) {
#pragma unroll
      for (int nt = 0; nt < 4; ++nt) {
        const int wpx = nt * 16 + col;
        if (wpx < WW) {
          __align__(8) _Float16 hv[4];
          hv[0] = (_Float16)fmaxf(acc[mt][nt][0] + b0, 0.f);
          hv[1] = (_Float16)fmaxf(acc[mt][nt][1] + b1_, 0.f);
          hv[2] = (_Float16)fmaxf(acc[mt][nt][2] + b2_, 0.f);
          hv[3] = (_Float16)fmaxf(acc[mt][nt][3] + b3, 0.f);
          _Float16* dst = out_h + (((size_t)b * PW + h + 1) * PW + wpx + 1) * C + o;
          *(uint2*)dst = *(uint2*)hv;
        }
      }
    } else {
#pragma unroll
      for (int nt = 0; nt < 4; ++nt) {
        const int wpx = nt * 16 + col;
        if (wpx < WW) {
          const int p = h * WW + wpx;
          const float bb[4] = {b0, b1_, b2_, b3};
#pragma unroll
          for (int r = 0; r < 4; ++r) {
            const size_t idx = ((size_t)(b * C + o + r)) * NN + p;
            out_f[idx] = (acc[mt][nt][r] + bb[r]) * amul[idx];
          }
        }
      }
    }
  }
}

// ---------------------------------------------------------------------------
// 3. fused Q/K/V linears: src [B][C][N] -> Q,K fp16 [B][N][C], Vt fp16 [B][C][N]
// ---------------------------------------------------------------------------
__global__ __launch_bounds__(256) void qkv_kernel(
    const float* __restrict__ src,
    const float* __restrict__ wq, const float* __restrict__ bq,
    const float* __restrict__ wk, const float* __restrict__ bk,
    const float* __restrict__ wv, const float* __restrict__ bv,
    __half* __restrict__ Q, __half* __restrict__ K, __half* __restrict__ Vt,
    float vscale)
{
  __shared__ float ss[C][20];
  const int tile = blockIdx.x;
  const int b = tile / NT;
  const int p0 = (tile % NT) * 16;
  const int t = threadIdx.x;
  {
    const float4* sb = (const float4*)(src + ((size_t)b * C + t) * NN + p0);
    float* row = ss[t];
#pragma unroll
    for (int g = 0; g < 4; ++g) {
      float4 v = sb[g];
      row[g * 4 + 0] = v.x; row[g * 4 + 1] = v.y;
      row[g * 4 + 2] = v.z; row[g * 4 + 3] = v.w;
    }
  }
  __syncthreads();

  const int o = t;
  float aq[16], ak[16], av[16];
  {
    const float q0 = bq[o], k0 = bk[o], v0 = bv[o];
#pragma unroll
    for (int p = 0; p < 16; ++p) { aq[p] = q0; ak[p] = k0; av[p] = v0; }
  }
  const float* wqr = wq + o * C;
  const float* wkr = wk + o * C;
  const float* wvr = wv + o * C;
  for (int k = 0; k < C; ++k) {
    const float fq = wqr[k], fk = wkr[k], fv = wvr[k];
    const float4* sr = (const float4*)ss[k];
#pragma unroll
    for (int g = 0; g < 4; ++g) {
      float4 s = sr[g];
      aq[g * 4 + 0] += fq * s.x; aq[g * 4 + 1] += fq * s.y; aq[g * 4 + 2] += fq * s.z; aq[g * 4 + 3] += fq * s.w;
      ak[g * 4 + 0] += fk * s.x; ak[g * 4 + 1] += fk * s.y; ak[g * 4 + 2] += fk * s.z; ak[g * 4 + 3] += fk * s.w;
      av[g * 4 + 0] += fv * s.x; av[g * 4 + 1] += fv * s.y; av[g * 4 + 2] += fv * s.z; av[g * 4 + 3] += fv * s.w;
    }
  }
#pragma unroll
  for (int p = 0; p < 16; ++p) {
    const size_t base = ((size_t)(b * NN) + p0 + p) * C + o;
    Q[base] = __float2half(aq[p]);
    K[base] = __float2half(ak[p]);
  }
  __align__(16) __half hv[16];
#pragma unroll
  for (int p = 0; p < 16; ++p) hv[p] = __float2half(av[p] * vscale);
  __half* vtp = Vt + ((size_t)(b * C) + o) * NN + p0;
  ((uint4*)vtp)[0] = ((uint4*)hv)[0];
  ((uint4*)vtp)[1] = ((uint4*)hv)[1];
}

// ---------------------------------------------------------------------------
// helper: 16B MFMA fragment from LDS as two ds_read_b64 (8B-aligned layouts)
// ---------------------------------------------------------------------------
__device__ inline half8 ld_frag(const _Float16* p) {
  union { half8 h8; half4v h4[2]; } u;
  u.h4[0] = *(const half4v*)p;
  u.h4[1] = *(const half4v*)(p + 4);
  return u.h8;
}

// ---------------------------------------------------------------------------
// 4. LDS-staged MFMA flash attention.
//    r5 flash2 was TA-bound: every operand load was a 64-cache-line gather
//    (lane stride 512B/6.3KB), re-issued by every wave. flash3 stages the
//    K-tile and V^T-tile in LDS with coalesced global loads (each line read
//    once per block), then gathers fragments via ds_read_b64 (padded rows:
//    Ks stride 260 halves, Vs stride 36 -> ~4-way bank aliasing, 8B-aligned).
//    Block = 2 waves x 16 q-rows, Bc = 32 keys, no key-split -> no merge.
// ---------------------------------------------------------------------------
__global__ __launch_bounds__(128) void flash3_kernel(
    const __half* __restrict__ Qg, const __half* __restrict__ Kg,
    const __half* __restrict__ Vtg, float* __restrict__ O, int accumulate)
{
  __shared__ _Float16 Ks[32][260];   // [key][ch]   16,640 B
  __shared__ _Float16 Vs[256][36];   // [ch][key]   18,432 B
  __shared__ _Float16 Pb[2][16][36]; // per-wave P   2,304 B

  const int bid = blockIdx.x;
  const int b = bid & 7;               // XCD-aligned batch
  const int q0 = (bid >> 3) * 32;      // 98 q-tiles of 32 rows
  const int t = threadIdx.x;           // 0..127
  const int w = t >> 6;
  const int lane = t & 63;
  const int col = lane & 15;
  const int quad = lane >> 4;

  // Q fragments (A-operand): rows q0 + w*16 + col  (one-time gather)
  const _Float16* Qp = (const _Float16*)Qg +
      ((size_t)(b * NN) + q0 + w * 16 + col) * C + quad * 8;
  half8 Qf[8];
#pragma unroll
  for (int s = 0; s < 8; ++s) Qf[s] = *(const half8*)(Qp + s * 32);

  floatx4 Ov[16];
#pragma unroll
  for (int n = 0; n < 16; ++n) Ov[n] = (floatx4){0.f, 0.f, 0.f, 0.f};
  float m[4] = {-1e30f, -1e30f, -1e30f, -1e30f};
  float l[4] = {0.f, 0.f, 0.f, 0.f};

  const _Float16* Kb = (const _Float16*)Kg + (size_t)(b * NN) * C;
  const _Float16* Vb = (const _Float16*)Vtg + (size_t)(b * C) * NN;

  for (int kb = 0; kb < 98; ++kb) {
    const int key0 = kb * 32;
    __syncthreads();   // prev compute done before overwriting tiles
    // ---- stage K tile: 32 keys x 512B, coalesced (8 lines / wave-inst) ----
    {
      half8 tk[8];
#pragma unroll
      for (int r = 0; r < 8; ++r) {
        const int flat = r * 128 + t;
        const int key = flat >> 5, c8 = flat & 31;
        tk[r] = *(const half8*)(Kb + (size_t)(key0 + key) * C + c8 * 8);
      }
#pragma unroll
      for (int r = 0; r < 8; ++r) {
        const int flat = r * 128 + t;
        const int key = flat >> 5, c8 = flat & 31;
        union { half8 h8; half4v h4[2]; } u; u.h8 = tk[r];
        *(half4v*)&Ks[key][c8 * 8] = u.h4[0];
        *(half4v*)&Ks[key][c8 * 8 + 4] = u.h4[1];
      }
      // ---- stage V^T tile: 256 ch x 64B ----
      half8 tv[8];
#pragma unroll
      for (int r = 0; r < 8; ++r) {
        const int flat = r * 128 + t;
        const int ch = flat >> 2, q = flat & 3;
        tv[r] = *(const half8*)(Vb + (size_t)ch * NN + key0 + q * 8);
      }
#pragma unroll
      for (int r = 0; r < 8; ++r) {
        const int flat = r * 128 + t;
        const int ch = flat >> 2, q = flat & 3;
        union { half8 h8; half4v h4[2]; } u; u.h8 = tv[r];
        *(half4v*)&Vs[ch][q * 8] = u.h4[0];
        *(half4v*)&Vs[ch][q * 8 + 4] = u.h4[1];
      }
    }
    __syncthreads();

    // ---- S = Q K^T (2 n-tiles of 16 keys) ----
    floatx4 Sv[2];
#pragma unroll
    for (int nt = 0; nt < 2; ++nt) {
      floatx4 acc = (floatx4){0.f, 0.f, 0.f, 0.f};
#pragma unroll
      for (int s = 0; s < 8; ++s) {
        const half8 bf = ld_frag(&Ks[nt * 16 + col][s * 32 + quad * 8]);
        acc = __builtin_amdgcn_mfma_f32_16x16x32_f16(Qf[s], bf, acc, 0, 0, 0);
      }
      Sv[nt] = acc * 0.0625f;   // 1/sqrt(256)
    }

    // ---- online softmax (rows = quad*4+r) ----
    float f[4];
#pragma unroll
    for (int r = 0; r < 4; ++r) {
      float v = fmaxf(Sv[0][r], Sv[1][r]);
      v = fmaxf(v, __shfl_xor(v, 1));
      v = fmaxf(v, __shfl_xor(v, 2));
      v = fmaxf(v, __shfl_xor(v, 4));
      v = fmaxf(v, __shfl_xor(v, 8));
      const float mn = fmaxf(m[r], v);
      f[r] = __expf(m[r] - mn);
      m[r] = mn;
    }
    float rowsum[4] = {0.f, 0.f, 0.f, 0.f};
#pragma unroll
    for (int nt = 0; nt < 2; ++nt) {
#pragma unroll
      for (int r = 0; r < 4; ++r) {
        const float p = __expf(Sv[nt][r] - m[r]);
        Sv[nt][r] = p;
        rowsum[r] += p;
      }
    }
#pragma unroll
    for (int r = 0; r < 4; ++r) {
      float s = rowsum[r];
      s += __shfl_xor(s, 1);
      s += __shfl_xor(s, 2);
      s += __shfl_xor(s, 4);
      s += __shfl_xor(s, 8);
      l[r] = l[r] * f[r] + s;
    }

    // ---- P -> LDS (per-wave), rescale O, O += P V ----
#pragma unroll
    for (int nt = 0; nt < 2; ++nt)
#pragma unroll
      for (int r = 0; r < 4; ++r)
        Pb[w][quad * 4 + r][nt * 16 + col] = (_Float16)Sv[nt][r];
    const floatx4 fv = {f[0], f[1], f[2], f[3]};
#pragma unroll
    for (int n = 0; n < 16; ++n) Ov[n] *= fv;
    const half8 pa = ld_frag(&Pb[w][col][quad * 8]);
#pragma unroll
    for (int nt2 = 0; nt2 < 16; ++nt2) {
      const half8 bv = ld_frag(&Vs[nt2 * 16 + col][quad * 8]);
      Ov[nt2] = __builtin_amdgcn_mfma_f32_16x16x32_f16(pa, bv, Ov[nt2], 0, 0, 0);
    }
  }

  // ---- finalize + write ----
  float inv[4];
#pragma unroll
  for (int r = 0; r < 4; ++r) inv[r] = 1.f / l[r];
#pragma unroll
  for (int nt2 = 0; nt2 < 16; ++nt2) {
#pragma unroll
    for (int r = 0; r < 4; ++r) {
      const float val = Ov[nt2][r] * inv[r];
      float* dst = O + ((size_t)(b * NN) + q0 + w * 16 + quad * 4 + r) * C +
                   nt2 * 16 + col;
      if (accumulate) *dst += val; else *dst = val;
    }
  }
}

// ---------------------------------------------------------------------------
// 5. out 1x1 conv + residual
// ---------------------------------------------------------------------------
__global__ __launch_bounds__(256) void outconv_kernel(
    const float* __restrict__ oattn, const float* __restrict__ ow,
    const float* __restrict__ ob, const float* __restrict__ x,
    float* __restrict__ o)
{
  __shared__ float os[16][260];
  const int tile = blockIdx.x;
  const int b = tile / NT;
  const int p0 = (tile % NT) * 16;
  const int t = threadIdx.x;
  {
    const int p = t >> 4, c0 = (t & 15) * 16;
    const float4* src = (const float4*)(oattn + ((size_t)(b * NN) + p0 + p) * C + c0);
    float4* dst = (float4*)(os[p] + c0);
#pragma unroll
    for (int g = 0; g < 4; ++g) dst[g] = src[g];
  }
  __syncthreads();

  const int oc = t;
  float acc[16];
  {
    const float bias = ob[oc];
#pragma unroll
    for (int p = 0; p < 16; ++p) acc[p] = bias;
  }
  const float4* wr = (const float4*)(ow + (size_t)oc * C);
  for (int k4 = 0; k4 < 64; ++k4) {
    const float4 w = wr[k4];
#pragma unroll
    for (int p = 0; p < 16; ++p) {
      const float4 v = *(const float4*)(os[p] + k4 * 4);
      acc[p] += w.x * v.x + w.y * v.y + w.z * v.z + w.w * v.w;
    }
  }
  const float4* xp4 = (const float4*)(x + ((size_t)b * C + oc) * NN + p0);
  float4* op4 = (float4*)(o + ((size_t)b * C + oc) * NN + p0);
#pragma unroll
  for (int g = 0; g < 4; ++g) {
    const float4 xv = xp4[g];
    op4[g] = make_float4(acc[g * 4 + 0] + xv.x, acc[g * 4 + 1] + xv.y,
                         acc[g * 4 + 2] + xv.z, acc[g * 4 + 3] + xv.w);
  }
}

// ---------------------------------------------------------------------------
// 6. BN stats
// ---------------------------------------------------------------------------
__global__ __launch_bounds__(256) void stats_kernel(
    const float* __restrict__ o, float* __restrict__ stats)
{
  const int c = blockIdx.x, t = threadIdx.x;
  float s = 0.f, sq = 0.f;
  for (int b = 0; b < BB; ++b) {
    const float* p = o + ((size_t)b * C + c) * NN;
    for (int idx = t; idx < NN; idx += 256) {
      const float v = p[idx];
      s += v; sq += v * v;
    }
  }
#pragma unroll
  for (int off = 32; off >= 1; off >>= 1) {
    s += __shfl_xor(s, off);
    sq += __shfl_xor(sq, off);
  }
  __shared__ float red[8];
  const int wv = t >> 6;
  if ((t & 63) == 0) { red[wv] = s; red[4 + wv] = sq; }
  __syncthreads();
  if (t == 0) {
    s = red[0] + red[1] + red[2] + red[3];
    sq = red[4] + red[5] + red[6] + red[7];
    stats[c] = s;
    stats[C + c] = sq;
  }
}

// ---------------------------------------------------------------------------
// 7. BN normalize -> d_out
// ---------------------------------------------------------------------------
__global__ __launch_bounds__(256) void bn_kernel(
    const float* __restrict__ o, const float* __restrict__ stats,
    const float* __restrict__ g, const float* __restrict__ bta,
    float* __restrict__ out)
{
  const size_t idx = (size_t)blockIdx.x * 256 + threadIdx.x;
  const float inv_n = 1.f / (float)(BB * NN);
  float4 v = ((const float4*)o)[idx];
  const int c = (int)((idx * 4 / NN) % C);
  const float mean = stats[c] * inv_n;
  const float var = stats[C + c] * inv_n - mean * mean;
  const float sc = rsqrtf(var + 1e-5f) * g[c];
  const float sh = bta[c] - mean * sc;
  v.x = v.x * sc + sh; v.y = v.y * sc + sh;
  v.z = v.z * sc + sh; v.w = v.w * sc + sh;
  ((float4*)out)[idx] = v;
}

// ---------------------------------------------------------------------------
extern "C" void kernel_launch(void* const* d_in, const int* in_sizes, int n_in,
                              void* d_out, int out_size, void* d_ws, size_t ws_size,
                              hipStream_t stream)
{
  const float* x    = (const float*)d_in[0];
  const float* hn   = (const float*)d_in[1];
  const float* w1   = (const float*)d_in[2];  const float* b1   = (const float*)d_in[3];
  const float* w2   = (const float*)d_in[4];  const float* b2   = (const float*)d_in[5];
  const float* wadj = (const float*)d_in[6];  const float* badj = (const float*)d_in[7];
  const float* tw1  = (const float*)d_in[8];  const float* tb1  = (const float*)d_in[9];
  const float* tw2  = (const float*)d_in[10]; const float* tb2  = (const float*)d_in[11];
  const float* qaw  = (const float*)d_in[12]; const float* qab  = (const float*)d_in[13];
  const float* kaw  = (const float*)d_in[14]; const float* kab  = (const float*)d_in[15];
  const float* vaw  = (const float*)d_in[16]; const float* vab  = (const float*)d_in[17];
  const float* qtw  = (const float*)d_in[18]; const float* qtb  = (const float*)d_in[19];
  const float* ktw  = (const float*)d_in[20]; const float* ktb  = (const float*)d_in[21];
  const float* vtw  = (const float*)d_in[22]; const float* vtb  = (const float*)d_in[23];
  const float* ow   = (const float*)d_in[24]; const float* obias= (const float*)d_in[25];
  const float* bng  = (const float*)d_in[26]; const float* bnb  = (const float*)d_in[27];

  // workspace plan (peak ~89.9 MB):
  //   [a 25.69][tt 25.69][hnpad 13.79+slack][t1pad 13.79+slack][w1h 1.18][w2h 1.18]
  //   after conv2, the hnpad..w2h region is dead -> Q/K/Vt (38.5) alias it.
  char* ws = (char*)d_ws;
  const size_t TENS  = (size_t)BB * C * NN * sizeof(float);        // 25,690,112
  const size_t HTENS = (size_t)BB * NN * C * sizeof(__half);       // 12,845,056
  const size_t PADT  = (size_t)BB * PW * PW * C * sizeof(_Float16) // 13,778,944
                       + 16384;                                    // OOB-read slack
  const size_t WT    = (size_t)9 * C * C * sizeof(_Float16);       // 1,179,648
  float*    a     = (float*)(ws);
  float*    tt    = (float*)(ws + TENS);
  _Float16* hnpad = (_Float16*)(ws + 2 * TENS);
  _Float16* t1pad = (_Float16*)(ws + 2 * TENS + PADT);
  _Float16* w1h   = (_Float16*)(ws + 2 * TENS + 2 * PADT);
  _Float16* w2h   = (_Float16*)(ws + 2 * TENS + 2 * PADT + WT);
  __half*   Q     = (__half*)(ws + 2 * TENS);            // aliases hnpad (dead)
  __half*   K     = (__half*)(ws + 2 * TENS + HTENS);
  __half*   Vt    = (__half*)(ws + 2 * TENS + 2 * HTENS);
  float*    stats = (float*)(ws + 2 * TENS + 3 * HTENS); // ~89.9 MB end

  const int PIX_TILES = BB * NT;           // 1568
  const int CONV_BLKS = BB * HH * 2;       // 896
  const int FLASH_BLKS = BB * (NN / 32);   // 784

  wprep_kernel<<<9 * C * C / 256, 256, 0, stream>>>(tw1, tw2, w1h, w2h);
  padzero_kernel<<<2 * BB * PW, 256, 0, stream>>>(hnpad, t1pad);
  hnprep_kernel<<<PIX_TILES, 256, 0, stream>>>(hn, hnpad);
  attr_kernel<<<PIX_TILES, 256, 0, stream>>>(x, w1, b1, w2, b2, wadj, badj, a);
  conv_mfma_kernel<<<CONV_BLKS, 256, 0, stream>>>(hnpad, w1h, tb1, nullptr, t1pad, nullptr, 0);
  conv_mfma_kernel<<<CONV_BLKS, 256, 0, stream>>>(t1pad, w2h, tb2, a, nullptr, tt, 1);

  qkv_kernel<<<PIX_TILES, 256, 0, stream>>>(a, qaw, qab, kaw, kab, vaw, vab, Q, K, Vt, 0.5f);
  float* oattn = a;   // a dead after qkv#1
  flash3_kernel<<<FLASH_BLKS, 128, 0, stream>>>(Q, K, Vt, oattn, 0);
  qkv_kernel<<<PIX_TILES, 256, 0, stream>>>(tt, qtw, qtb, ktw, ktb, vtw, vtb, Q, K, Vt, 0.5f);
  flash3_kernel<<<FLASH_BLKS, 128, 0, stream>>>(Q, K, Vt, oattn, 1);

  float* o = tt;      // tt dead after qkv#2
  outconv_kernel<<<PIX_TILES, 256, 0, stream>>>(oattn, ow, obias, x, o);
  stats_kernel<<<C, 256, 0, stream>>>(o, stats);
  bn_kernel<<<(BB * C * NN / 4) / 256, 256, 0, stream>>>(o, stats, bng, bnb, (float*)d_out);
}

// Round 7
// 2146.247 us; speedup vs baseline: 6.6503x; 1.5055x over previous
//
#include <hip/hip_runtime.h>
#include <hip/hip_fp16.h>

#define BB 8
#define C 256
#define HH 56
#define WW 56
#define NN 3136      // HH*WW
#define RR 16
#define NT (NN/16)   // 196 pixel-tiles per image
#define PW 58        // padded spatial width/height

typedef _Float16 half8 __attribute__((ext_vector_type(8)));
typedef _Float16 half4v __attribute__((ext_vector_type(4)));
typedef float floatx4 __attribute__((ext_vector_type(4)));

// ---------------------------------------------------------------------------
// 1. attr branch fused: a = adj( concat( relu(W2 relu(W1 x)), x ) )
// ---------------------------------------------------------------------------
__global__ __launch_bounds__(256) void attr_kernel(
    const float* __restrict__ x,
    const float* __restrict__ w1, const float* __restrict__ b1,
    const float* __restrict__ w2, const float* __restrict__ b2,
    const float* __restrict__ wadj, const float* __restrict__ badj,
    float* __restrict__ a_out)
{
  __shared__ float xs[C][20];
  __shared__ float a2s[C][20];
  __shared__ float a1s[RR][20];
  const int tile = blockIdx.x;
  const int b = tile / NT;
  const int p0 = (tile % NT) * 16;
  const int t = threadIdx.x;

  {
    const float* xb = x + ((size_t)b * C + t) * NN + p0;
    const float4* xb4 = (const float4*)xb;
    float* row = xs[t];
#pragma unroll
    for (int g = 0; g < 4; ++g) {
      float4 v = xb4[g];
      row[g * 4 + 0] = v.x; row[g * 4 + 1] = v.y;
      row[g * 4 + 2] = v.z; row[g * 4 + 3] = v.w;
    }
  }
  __syncthreads();

  {
    const int r = t & 15, pp = t >> 4;
    float acc = b1[r];
    const float* wr = w1 + r * C;
    for (int c = 0; c < C; ++c) acc += wr[c] * xs[c][pp];
    a1s[r][pp] = fmaxf(acc, 0.f);
  }
  __syncthreads();

  {
    const int o = t;
    float acc[16];
    const float bias = b2[o];
#pragma unroll
    for (int p = 0; p < 16; ++p) acc[p] = bias;
    const float* wr = w2 + o * RR;
    for (int k = 0; k < RR; ++k) {
      const float w = wr[k];
#pragma unroll
      for (int p = 0; p < 16; ++p) acc[p] += w * a1s[k][p];
    }
    float* row = a2s[o];
#pragma unroll
    for (int p = 0; p < 16; ++p) row[p] = fmaxf(acc[p], 0.f);
  }
  __syncthreads();

  {
    const int o = t;
    float acc[16];
    const float bias = badj[o];
#pragma unroll
    for (int p = 0; p < 16; ++p) acc[p] = bias;
    const float* wr = wadj + (size_t)o * (2 * C);
    for (int k = 0; k < C; ++k) {
      const float w = wr[k];
      const float4* ar = (const float4*)a2s[k];
#pragma unroll
      for (int g = 0; g < 4; ++g) {
        float4 v = ar[g];
        acc[g * 4 + 0] += w * v.x; acc[g * 4 + 1] += w * v.y;
        acc[g * 4 + 2] += w * v.z; acc[g * 4 + 3] += w * v.w;
      }
    }
    for (int k = 0; k < C; ++k) {
      const float w = wr[C + k];
      const float4* xr = (const float4*)xs[k];
#pragma unroll
      for (int g = 0; g < 4; ++g) {
        float4 v = xr[g];
        acc[g * 4 + 0] += w * v.x; acc[g * 4 + 1] += w * v.y;
        acc[g * 4 + 2] += w * v.z; acc[g * 4 + 3] += w * v.w;
      }
    }
    float* op = a_out + ((size_t)b * C + o) * NN + p0;
    float4* op4 = (float4*)op;
#pragma unroll
    for (int g = 0; g < 4; ++g)
      op4[g] = make_float4(acc[g * 4 + 0], acc[g * 4 + 1], acc[g * 4 + 2], acc[g * 4 + 3]);
  }
}

// ---------------------------------------------------------------------------
// 2a. conv weight prep: w1h[tap][o][c] = tw1[o][c][tap] (fp16)
//     w2h[tap][o][c] = tw2[o][c][8-tap]  (convT spatial flip folded in)
// ---------------------------------------------------------------------------
__global__ __launch_bounds__(256) void wprep_kernel(
    const float* __restrict__ tw1, const float* __restrict__ tw2,
    _Float16* __restrict__ w1h, _Float16* __restrict__ w2h)
{
  const int i = blockIdx.x * 256 + threadIdx.x;   // over 9*256*256
  const int tap = i >> 16;
  const int rem = i & 65535;
  const int o = rem >> 8;
  const int c = rem & 255;
  w1h[i] = (_Float16)tw1[((size_t)o * C + c) * 9 + tap];
  w2h[i] = (_Float16)tw2[((size_t)o * C + c) * 9 + (8 - tap)];
}

// ---------------------------------------------------------------------------
// 2a'. 1x1 weight prep: 7 C*C fp32 matrices -> fp16, same [o][c] layout.
//      Order: qa,ka,va, qt,kt,vt, ow
// ---------------------------------------------------------------------------
__global__ __launch_bounds__(256) void wprep_qkv_kernel(
    const float* __restrict__ m0, const float* __restrict__ m1,
    const float* __restrict__ m2, const float* __restrict__ m3,
    const float* __restrict__ m4, const float* __restrict__ m5,
    const float* __restrict__ m6, _Float16* __restrict__ Whall)
{
  const int i = blockIdx.x * 256 + threadIdx.x;   // over 7*65536
  const int mat = i >> 16, rem = i & 65535;
  const float* s;
  switch (mat) {
    case 0: s = m0; break; case 1: s = m1; break; case 2: s = m2; break;
    case 3: s = m3; break; case 4: s = m4; break; case 5: s = m5; break;
    default: s = m6; break;
  }
  Whall[i] = (_Float16)s[rem];
}

// ---------------------------------------------------------------------------
// 2b. zero the pad border of both padded-NHWC fp16 buffers
// ---------------------------------------------------------------------------
__global__ __launch_bounds__(256) void padzero_kernel(
    _Float16* __restrict__ buf1, _Float16* __restrict__ buf2)
{
  const int bid = blockIdx.x;                 // 2 * BB * PW
  _Float16* buf = (bid < BB * PW) ? buf1 : buf2;
  const int rb = bid % (BB * PW);
  const int b = rb / PW, r = rb % PW;
  _Float16* row = buf + ((size_t)b * PW + r) * PW * C;
  const float4 z = make_float4(0.f, 0.f, 0.f, 0.f);
  if (r == 0 || r == PW - 1) {
    for (int i = threadIdx.x; i < PW * C / 8; i += 256) ((float4*)row)[i] = z;
  } else {
    const int i = threadIdx.x;
    if (i < 32) ((float4*)row)[i] = z;                       // col 0
    else if (i < 64) ((float4*)(row + (PW - 1) * C))[i - 32] = z;  // col 57
  }
}

// ---------------------------------------------------------------------------
// 2c. hn (fp32 NCHW) -> hnpad (fp16 padded NHWC) interior, via LDS transpose
// ---------------------------------------------------------------------------
__global__ __launch_bounds__(256) void hnprep_kernel(
    const float* __restrict__ hn, _Float16* __restrict__ hnpad)
{
  __shared__ float xs[C][17];
  const int tile = blockIdx.x;
  const int b = tile / NT;
  const int p0 = (tile % NT) * 16;
  const int t = threadIdx.x;
  {
    const float4* sb = (const float4*)(hn + ((size_t)b * C + t) * NN + p0);
    float* row = xs[t];
#pragma unroll
    for (int g = 0; g < 4; ++g) {
      float4 v = sb[g];
      row[g * 4 + 0] = v.x; row[g * 4 + 1] = v.y;
      row[g * 4 + 2] = v.z; row[g * 4 + 3] = v.w;
    }
  }
  __syncthreads();
  const int p = t >> 4, c0 = (t & 15) * 16;
  const int pg = p0 + p;
  const int h = pg / WW, w = pg % WW;
  __align__(16) _Float16 tmp[16];
#pragma unroll
  for (int j = 0; j < 16; ++j) tmp[j] = (_Float16)xs[c0 + j][p];
  _Float16* dst = hnpad + (((size_t)b * PW + h + 1) * PW + w + 1) * C + c0;
  ((uint4*)dst)[0] = ((uint4*)tmp)[0];
  ((uint4*)dst)[1] = ((uint4*)tmp)[1];
}

// ---------------------------------------------------------------------------
// 2d. conv3x3 as 9-tap MFMA GEMM.  XCD-swizzled (b = bid & 7).
// ---------------------------------------------------------------------------
__global__ __launch_bounds__(256) void conv_mfma_kernel(
    const _Float16* __restrict__ inpad, const _Float16* __restrict__ wh,
    const float* __restrict__ bias, const float* __restrict__ amul,
    _Float16* __restrict__ out_h, float* __restrict__ out_f, int mode)
{
  const int bid = blockIdx.x;          // BB*56*2
  const int b = bid & 7;               // XCD-aligned batch
  const int rest = bid >> 3;           // 0..111
  const int ohalf = rest & 1;
  const int h = rest >> 1;
  const int t = threadIdx.x;
  const int wave = t >> 6, lane = t & 63;
  const int col = lane & 15, quad = lane >> 4;
  const int o_base = ohalf * 128 + wave * 32;

  floatx4 acc[2][4];
#pragma unroll
  for (int mt = 0; mt < 2; ++mt)
#pragma unroll
    for (int nt = 0; nt < 4; ++nt) acc[mt][nt] = (floatx4){0.f, 0.f, 0.f, 0.f};

  const _Float16* inb = inpad + (size_t)b * PW * PW * C;

  for (int tap = 0; tap < 9; ++tap) {
    const int dy = tap / 3;
    const int dx = tap - dy * 3;
    const _Float16* wtap = wh + (size_t)tap * C * C + quad * 8;
    const _Float16* inrow = inb + ((size_t)(h + dy) * PW + dx + col) * C + quad * 8;
    for (int kc = 0; kc < 8; ++kc) {
      const int c0 = kc * 32;
      const half8 A0 = *(const half8*)(wtap + (size_t)(o_base + col) * C + c0);
      const half8 A1 = *(const half8*)(wtap + (size_t)(o_base + 16 + col) * C + c0);
#pragma unroll
      for (int nt = 0; nt < 4; ++nt) {
        const half8 Bv = *(const half8*)(inrow + (size_t)(nt * 16) * C + c0);
        acc[0][nt] = __builtin_amdgcn_mfma_f32_16x16x32_f16(A0, Bv, acc[0][nt], 0, 0, 0);
        acc[1][nt] = __builtin_amdgcn_mfma_f32_16x16x32_f16(A1, Bv, acc[1][nt], 0, 0, 0);
      }
    }
  }

#pragma unroll
  for (int mt = 0; mt < 2; ++mt) {
    const int o = o_base + mt * 16 + quad * 4;
    const float* bp = bias + o;
    const float b0 = bp[0], b1_ = bp[1], b2_ = bp[2], b3 = bp[3];
    if (mode == 0) {
#pragma unroll
      for (int nt = 0; nt < 4; ++nt) {
        const int wpx = nt * 16 + col;
        if (wpx < WW) {
          __align__(8) _Float16 hv[4];
          hv[0] = (_Float16)fmaxf(acc[mt][nt][0] + b0, 0.f);
          hv[1] = (_Float16)fmaxf(acc[mt][nt][1] + b1_, 0.f);
          hv[2] = (_Float16)fmaxf(acc[mt][nt][2] + b2_, 0.f);
          hv[3] = (_Float16)fmaxf(acc[mt][nt][3] + b3, 0.f);
          _Float16* dst = out_h + (((size_t)b * PW + h + 1) * PW + wpx + 1) * C + o;
          *(uint2*)dst = *(uint2*)hv;
        }
      }
    } else {
#pragma unroll
      for (int nt = 0; nt < 4; ++nt) {
        const int wpx = nt * 16 + col;
        if (wpx < WW) {
          const int p = h * WW + wpx;
          const float bb[4] = {b0, b1_, b2_, b3};
#pragma unroll
          for (int r = 0; r < 4; ++r) {
            const size_t idx = ((size_t)(b * C + o + r)) * NN + p;
            out_f[idx] = (acc[mt][nt][r] + bb[r]) * amul[idx];
          }
        }
      }
    }
  }
}

// ---------------------------------------------------------------------------
// helper: 16B MFMA fragment from LDS as two ds_read_b64 (8B-aligned layouts)
// ---------------------------------------------------------------------------
__device__ inline half8 ld_frag(const _Float16* p) {
  union { half8 h8; half4v h4[2]; } u;
  u.h4[0] = *(const half4v*)p;
  u.h4[1] = *(const half4v*)(p + 4);
  return u.h8;
}

// ---------------------------------------------------------------------------
// 3. qkv as MFMA GEMM. r6 qkv was TA-bound (per-thread weight rows, 64-line
//    gathers). Here: A = fp16 weights [s][o][c] (contiguous rows, L2-hot),
//    B = src tile staged in LDS as fp16 [px][ch], one pass for Q,K,V.
//    Block = 4 waves x (12 m-tiles x 2 n-tiles), 32-px tile, XCD-swizzled.
//    Epilogue: Q,K -> [B][N][C] (8B packed stores), V*0.5 -> Vt [B][C][N].
// ---------------------------------------------------------------------------
__global__ __launch_bounds__(256) void qkv_mfma_kernel(
    const float* __restrict__ src, const _Float16* __restrict__ Wh,
    const float* __restrict__ bq, const float* __restrict__ bk,
    const float* __restrict__ bv,
    __half* __restrict__ Q, __half* __restrict__ K, __half* __restrict__ Vt)
{
  __shared__ _Float16 Ss[32][264];     // [px][ch]  16,896 B
  const int bid = blockIdx.x;          // 784
  const int b = bid & 7;
  const int p0 = (bid >> 3) * 32;
  const int t = threadIdx.x;
  const int w = t >> 6, lane = t & 63;
  const int col = lane & 15, quad = lane >> 4;

  // stage src tile: fp32 [C][N] -> fp16 LDS [px][ch] (thread t = channel t)
  {
    const float4* sp = (const float4*)(src + ((size_t)b * C + t) * NN + p0);
    float v[32];
#pragma unroll
    for (int g = 0; g < 8; ++g) {
      const float4 f = sp[g];
      v[g * 4 + 0] = f.x; v[g * 4 + 1] = f.y;
      v[g * 4 + 2] = f.z; v[g * 4 + 3] = f.w;
    }
#pragma unroll
    for (int px = 0; px < 32; ++px) Ss[px][t] = (_Float16)v[px];
  }
  __syncthreads();

  floatx4 acc[12][2];
#pragma unroll
  for (int i = 0; i < 12; ++i)
#pragma unroll
    for (int nt = 0; nt < 2; ++nt) acc[i][nt] = (floatx4){0.f, 0.f, 0.f, 0.f};

  for (int k0 = 0; k0 < 256; k0 += 32) {
    half8 bf[2];
    bf[0] = ld_frag(&Ss[col][k0 + quad * 8]);
    bf[1] = ld_frag(&Ss[16 + col][k0 + quad * 8]);
#pragma unroll
    for (int i = 0; i < 12; ++i) {
      const int mtg = w * 12 + i;      // 0..47: [0,16)=Q, [16,32)=K, [32,48)=V
      // Wh flat: s*65536 + (mt*16+col)*256 + k  ==  mtg*4096 + col*256 + k
      const half8 af = *(const half8*)(Wh + (size_t)mtg * 4096 + col * 256 + k0 + quad * 8);
      acc[i][0] = __builtin_amdgcn_mfma_f32_16x16x32_f16(af, bf[0], acc[i][0], 0, 0, 0);
      acc[i][1] = __builtin_amdgcn_mfma_f32_16x16x32_f16(af, bf[1], acc[i][1], 0, 0, 0);
    }
  }

#pragma unroll
  for (int i = 0; i < 12; ++i) {
    const int mtg = w * 12 + i;
    const int s = mtg >> 4;
    const int crow = (mtg & 15) * 16 + quad * 4;    // c_out base of this lane
    const float* bp = (s == 0 ? bq : (s == 1 ? bk : bv)) + crow;
    const float4 b4 = *(const float4*)bp;
    const float bb[4] = {b4.x, b4.y, b4.z, b4.w};
#pragma unroll
    for (int nt = 0; nt < 2; ++nt) {
      const int px = p0 + nt * 16 + col;
      if (s == 2) {
#pragma unroll
        for (int r = 0; r < 4; ++r)
          Vt[((size_t)(b * C) + crow + r) * NN + px] =
              __float2half((acc[i][nt][r] + bb[r]) * 0.5f);
      } else {
        __half* dst = (s == 0 ? Q : K) + ((size_t)(b * NN) + px) * C + crow;
        __align__(8) __half hv[4];
#pragma unroll
        for (int r = 0; r < 4; ++r) hv[r] = __float2half(acc[i][nt][r] + bb[r]);
        *(uint2*)dst = *(uint2*)hv;
      }
    }
  }
}

// ---------------------------------------------------------------------------
// 4. LDS-staged MFMA flash attention.  Output now fp16 [B][N][C] (O16) so
//    outconv can consume it as direct contiguous B-fragments.
// ---------------------------------------------------------------------------
__global__ __launch_bounds__(128) void flash3_kernel(
    const __half* __restrict__ Qg, const __half* __restrict__ Kg,
    const __half* __restrict__ Vtg, __half* __restrict__ O16, int accumulate)
{
  __shared__ _Float16 Ks[32][260];   // [key][ch]   16,640 B
  __shared__ _Float16 Vs[256][36];   // [ch][key]   18,432 B
  __shared__ _Float16 Pb[2][16][36]; // per-wave P   2,304 B

  const int bid = blockIdx.x;
  const int b = bid & 7;               // XCD-aligned batch
  const int q0 = (bid >> 3) * 32;      // 98 q-tiles of 32 rows
  const int t = threadIdx.x;           // 0..127
  const int w = t >> 6;
  const int lane = t & 63;
  const int col = lane & 15;
  const int quad = lane >> 4;

  const _Float16* Qp = (const _Float16*)Qg +
      ((size_t)(b * NN) + q0 + w * 16 + col) * C + quad * 8;
  half8 Qf[8];
#pragma unroll
  for (int s = 0; s < 8; ++s) Qf[s] = *(const half8*)(Qp + s * 32);

  floatx4 Ov[16];
#pragma unroll
  for (int n = 0; n < 16; ++n) Ov[n] = (floatx4){0.f, 0.f, 0.f, 0.f};
  float m[4] = {-1e30f, -1e30f, -1e30f, -1e30f};
  float l[4] = {0.f, 0.f, 0.f, 0.f};

  const _Float16* Kb = (const _Float16*)Kg + (size_t)(b * NN) * C;
  const _Float16* Vb = (const _Float16*)Vtg + (size_t)(b * C) * NN;

  for (int kb = 0; kb < 98; ++kb) {
    const int key0 = kb * 32;
    __syncthreads();
    {
      half8 tk[8];
#pragma unroll
      for (int r = 0; r < 8; ++r) {
        const int flat = r * 128 + t;
        const int key = flat >> 5, c8 = flat & 31;
        tk[r] = *(const half8*)(Kb + (size_t)(key0 + key) * C + c8 * 8);
      }
#pragma unroll
      for (int r = 0; r < 8; ++r) {
        const int flat = r * 128 + t;
        const int key = flat >> 5, c8 = flat & 31;
        union { half8 h8; half4v h4[2]; } u; u.h8 = tk[r];
        *(half4v*)&Ks[key][c8 * 8] = u.h4[0];
        *(half4v*)&Ks[key][c8 * 8 + 4] = u.h4[1];
      }
      half8 tv[8];
#pragma unroll
      for (int r = 0; r < 8; ++r) {
        const int flat = r * 128 + t;
        const int ch = flat >> 2, q = flat & 3;
        tv[r] = *(const half8*)(Vb + (size_t)ch * NN + key0 + q * 8);
      }
#pragma unroll
      for (int r = 0; r < 8; ++r) {
        const int flat = r * 128 + t;
        const int ch = flat >> 2, q = flat & 3;
        union { half8 h8; half4v h4[2]; } u; u.h8 = tv[r];
        *(half4v*)&Vs[ch][q * 8] = u.h4[0];
        *(half4v*)&Vs[ch][q * 8 + 4] = u.h4[1];
      }
    }
    __syncthreads();

    floatx4 Sv[2];
#pragma unroll
    for (int nt = 0; nt < 2; ++nt) {
      floatx4 acc = (floatx4){0.f, 0.f, 0.f, 0.f};
#pragma unroll
      for (int s = 0; s < 8; ++s) {
        const half8 bf = ld_frag(&Ks[nt * 16 + col][s * 32 + quad * 8]);
        acc = __builtin_amdgcn_mfma_f32_16x16x32_f16(Qf[s], bf, acc, 0, 0, 0);
      }
      Sv[nt] = acc * 0.0625f;   // 1/sqrt(256)
    }

    float f[4];
#pragma unroll
    for (int r = 0; r < 4; ++r) {
      float v = fmaxf(Sv[0][r], Sv[1][r]);
      v = fmaxf(v, __shfl_xor(v, 1));
      v = fmaxf(v, __shfl_xor(v, 2));
      v = fmaxf(v, __shfl_xor(v, 4));
      v = fmaxf(v, __shfl_xor(v, 8));
      const float mn = fmaxf(m[r], v);
      f[r] = __expf(m[r] - mn);
      m[r] = mn;
    }
    float rowsum[4] = {0.f, 0.f, 0.f, 0.f};
#pragma unroll
    for (int nt = 0; nt < 2; ++nt) {
#pragma unroll
      for (int r = 0; r < 4; ++r) {
        const float p = __expf(Sv[nt][r] - m[r]);
        Sv[nt][r] = p;
        rowsum[r] += p;
      }
    }
#pragma unroll
    for (int r = 0; r < 4; ++r) {
      float s = rowsum[r];
      s += __shfl_xor(s, 1);
      s += __shfl_xor(s, 2);
      s += __shfl_xor(s, 4);
      s += __shfl_xor(s, 8);
      l[r] = l[r] * f[r] + s;
    }

#pragma unroll
    for (int nt = 0; nt < 2; ++nt)
#pragma unroll
      for (int r = 0; r < 4; ++r)
        Pb[w][quad * 4 + r][nt * 16 + col] = (_Float16)Sv[nt][r];
    const floatx4 fv = {f[0], f[1], f[2], f[3]};
#pragma unroll
    for (int n = 0; n < 16; ++n) Ov[n] *= fv;
    const half8 pa = ld_frag(&Pb[w][col][quad * 8]);
#pragma unroll
    for (int nt2 = 0; nt2 < 16; ++nt2) {
      const half8 bv = ld_frag(&Vs[nt2 * 16 + col][quad * 8]);
      Ov[nt2] = __builtin_amdgcn_mfma_f32_16x16x32_f16(pa, bv, Ov[nt2], 0, 0, 0);
    }
  }

  float inv[4];
#pragma unroll
  for (int r = 0; r < 4; ++r) inv[r] = 1.f / l[r];
#pragma unroll
  for (int nt2 = 0; nt2 < 16; ++nt2) {
#pragma unroll
    for (int r = 0; r < 4; ++r) {
      const float val = Ov[nt2][r] * inv[r];
      __half* dst = O16 + ((size_t)(b * NN) + q0 + w * 16 + quad * 4 + r) * C +
                    nt2 * 16 + col;
      if (accumulate) *dst = __float2half(val + __half2float(*dst));
      else *dst = __float2half(val);
    }
  }
}

// ---------------------------------------------------------------------------
// 5. out 1x1 conv + residual as MFMA GEMM.
//    A = fp16 ow rows (global), B = O16 [N][C] direct contiguous fragments.
//    Epilogue: + bias + x, write fp32 NCHW o (pre-BN).
// ---------------------------------------------------------------------------
__global__ __launch_bounds__(256) void outconv_mfma_kernel(
    const __half* __restrict__ O16, const _Float16* __restrict__ owh,
    const float* __restrict__ ob, const float* __restrict__ x,
    float* __restrict__ o)
{
  const int bid = blockIdx.x;          // 392
  const int b = bid & 7;
  const int p0 = (bid >> 3) * 64;
  const int t = threadIdx.x;
  const int w = t >> 6, lane = t & 63;
  const int col = lane & 15, quad = lane >> 4;

  floatx4 acc[4][4];
#pragma unroll
  for (int mt = 0; mt < 4; ++mt)
#pragma unroll
    for (int nt = 0; nt < 4; ++nt) acc[mt][nt] = (floatx4){0.f, 0.f, 0.f, 0.f};

  const _Float16* Ob = (const _Float16*)O16 + (size_t)(b * NN) * C;

  for (int k0 = 0; k0 < 256; k0 += 32) {
    half8 bf[4];
#pragma unroll
    for (int nt = 0; nt < 4; ++nt)
      bf[nt] = *(const half8*)(Ob + (size_t)(p0 + nt * 16 + col) * C + k0 + quad * 8);
#pragma unroll
    for (int mt = 0; mt < 4; ++mt) {
      const int crow = w * 64 + mt * 16 + col;
      const half8 af = *(const half8*)(owh + (size_t)crow * 256 + k0 + quad * 8);
#pragma unroll
      for (int nt = 0; nt < 4; ++nt)
        acc[mt][nt] = __builtin_amdgcn_mfma_f32_16x16x32_f16(af, bf[nt], acc[mt][nt], 0, 0, 0);
    }
  }

#pragma unroll
  for (int mt = 0; mt < 4; ++mt) {
    const int c0 = w * 64 + mt * 16 + quad * 4;
    const float4 b4 = *(const float4*)(ob + c0);
    const float bb[4] = {b4.x, b4.y, b4.z, b4.w};
#pragma unroll
    for (int nt = 0; nt < 4; ++nt) {
      const int px = p0 + nt * 16 + col;
#pragma unroll
      for (int r = 0; r < 4; ++r) {
        const size_t idx = ((size_t)(b * C) + c0 + r) * NN + px;
        o[idx] = acc[mt][nt][r] + bb[r] + x[idx];
      }
    }
  }
}

// ---------------------------------------------------------------------------
// 6. BN stats
// ---------------------------------------------------------------------------
__global__ __launch_bounds__(256) void stats_kernel(
    const float* __restrict__ o, float* __restrict__ stats)
{
  const int c = blockIdx.x, t = threadIdx.x;
  float s = 0.f, sq = 0.f;
  for (int b = 0; b < BB; ++b) {
    const float* p = o + ((size_t)b * C + c) * NN;
    for (int idx = t; idx < NN; idx += 256) {
      const float v = p[idx];
      s += v; sq += v * v;
    }
  }
#pragma unroll
  for (int off = 32; off >= 1; off >>= 1) {
    s += __shfl_xor(s, off);
    sq += __shfl_xor(sq, off);
  }
  __shared__ float red[8];
  const int wv = t >> 6;
  if ((t & 63) == 0) { red[wv] = s; red[4 + wv] = sq; }
  __syncthreads();
  if (t == 0) {
    s = red[0] + red[1] + red[2] + red[3];
    sq = red[4] + red[5] + red[6] + red[7];
    stats[c] = s;
    stats[C + c] = sq;
  }
}

// ---------------------------------------------------------------------------
// 7. BN normalize -> d_out
// ---------------------------------------------------------------------------
__global__ __launch_bounds__(256) void bn_kernel(
    const float* __restrict__ o, const float* __restrict__ stats,
    const float* __restrict__ g, const float* __restrict__ bta,
    float* __restrict__ out)
{
  const size_t idx = (size_t)blockIdx.x * 256 + threadIdx.x;
  const float inv_n = 1.f / (float)(BB * NN);
  float4 v = ((const float4*)o)[idx];
  const int c = (int)((idx * 4 / NN) % C);
  const float mean = stats[c] * inv_n;
  const float var = stats[C + c] * inv_n - mean * mean;
  const float sc = rsqrtf(var + 1e-5f) * g[c];
  const float sh = bta[c] - mean * sc;
  v.x = v.x * sc + sh; v.y = v.y * sc + sh;
  v.z = v.z * sc + sh; v.w = v.w * sc + sh;
  ((float4*)out)[idx] = v;
}

// ---------------------------------------------------------------------------
extern "C" void kernel_launch(void* const* d_in, const int* in_sizes, int n_in,
                              void* d_out, int out_size, void* d_ws, size_t ws_size,
                              hipStream_t stream)
{
  const float* x    = (const float*)d_in[0];
  const float* hn   = (const float*)d_in[1];
  const float* w1   = (const float*)d_in[2];  const float* b1   = (const float*)d_in[3];
  const float* w2   = (const float*)d_in[4];  const float* b2   = (const float*)d_in[5];
  const float* wadj = (const float*)d_in[6];  const float* badj = (const float*)d_in[7];
  const float* tw1  = (const float*)d_in[8];  const float* tb1  = (const float*)d_in[9];
  const float* tw2  = (const float*)d_in[10]; const float* tb2  = (const float*)d_in[11];
  const float* qaw  = (const float*)d_in[12]; const float* qab  = (const float*)d_in[13];
  const float* kaw  = (const float*)d_in[14]; const float* kab  = (const float*)d_in[15];
  const float* vaw  = (const float*)d_in[16]; const float* vab  = (const float*)d_in[17];
  const float* qtw  = (const float*)d_in[18]; const float* qtb  = (const float*)d_in[19];
  const float* ktw  = (const float*)d_in[20]; const float* ktb  = (const float*)d_in[21];
  const float* vtw  = (const float*)d_in[22]; const float* vtb  = (const float*)d_in[23];
  const float* ow   = (const float*)d_in[24]; const float* obias= (const float*)d_in[25];
  const float* bng  = (const float*)d_in[26]; const float* bnb  = (const float*)d_in[27];

  // workspace plan (peak ~90.8 MB; 115.6 MB proven in r2/r3):
  //   [a 25.69][tt 25.69][hnpad 13.79+slk][t1pad 13.79+slk][w1h 1.18][w2h 1.18]
  //   Q/K/Vt (38.5) alias hnpad.. after convs; O16 (12.85) aliases a after qkv#1.
  //   [stats 4KB][Whall 0.92MB] appended at the end.
  char* ws = (char*)d_ws;
  const size_t TENS  = (size_t)BB * C * NN * sizeof(float);        // 25,690,112
  const size_t HTENS = (size_t)BB * NN * C * sizeof(__half);       // 12,845,056
  const size_t PADT  = (size_t)BB * PW * PW * C * sizeof(_Float16) // 13,778,944
                       + 16384;                                    // OOB-read slack
  const size_t WT    = (size_t)9 * C * C * sizeof(_Float16);       // 1,179,648
  float*    a     = (float*)(ws);
  float*    tt    = (float*)(ws + TENS);
  _Float16* hnpad = (_Float16*)(ws + 2 * TENS);
  _Float16* t1pad = (_Float16*)(ws + 2 * TENS + PADT);
  _Float16* w1h   = (_Float16*)(ws + 2 * TENS + 2 * PADT);
  _Float16* w2h   = (_Float16*)(ws + 2 * TENS + 2 * PADT + WT);
  __half*   Q     = (__half*)(ws + 2 * TENS);            // aliases hnpad (dead)
  __half*   K     = (__half*)(ws + 2 * TENS + HTENS);
  __half*   Vt    = (__half*)(ws + 2 * TENS + 2 * HTENS);
  float*    stats = (float*)(ws + 2 * TENS + 3 * HTENS);
  _Float16* Whall = (_Float16*)(ws + 2 * TENS + 3 * HTENS + 4096); // 7*65536 fp16
  __half*   O16   = (__half*)a;    // a dead after qkv#1 reads it

  const int PIX_TILES = BB * NT;           // 1568
  const int CONV_BLKS = BB * HH * 2;       // 896
  const int FLASH_BLKS = BB * (NN / 32);   // 784
  const int QKV_BLKS = BB * (NN / 32);     // 784
  const int OUT_BLKS = BB * (NN / 64);     // 392

  wprep_kernel<<<9 * C * C / 256, 256, 0, stream>>>(tw1, tw2, w1h, w2h);
  wprep_qkv_kernel<<<7 * C * C / 256, 256, 0, stream>>>(
      qaw, kaw, vaw, qtw, ktw, vtw, ow, Whall);
  padzero_kernel<<<2 * BB * PW, 256, 0, stream>>>(hnpad, t1pad);
  hnprep_kernel<<<PIX_TILES, 256, 0, stream>>>(hn, hnpad);
  attr_kernel<<<PIX_TILES, 256, 0, stream>>>(x, w1, b1, w2, b2, wadj, badj, a);
  conv_mfma_kernel<<<CONV_BLKS, 256, 0, stream>>>(hnpad, w1h, tb1, nullptr, t1pad, nullptr, 0);
  conv_mfma_kernel<<<CONV_BLKS, 256, 0, stream>>>(t1pad, w2h, tb2, a, nullptr, tt, 1);

  qkv_mfma_kernel<<<QKV_BLKS, 256, 0, stream>>>(a, Whall, qab, kab, vab, Q, K, Vt);
  flash3_kernel<<<FLASH_BLKS, 128, 0, stream>>>(Q, K, Vt, O16, 0);
  qkv_mfma_kernel<<<QKV_BLKS, 256, 0, stream>>>(tt, Whall + 3 * 65536, qtb, ktb, vtb, Q, K, Vt);
  flash3_kernel<<<FLASH_BLKS, 128, 0, stream>>>(Q, K, Vt, O16, 1);

  float* o = tt;      // tt dead after qkv#2
  outconv_mfma_kernel<<<OUT_BLKS, 256, 0, stream>>>(O16, Whall + 6 * 65536, obias, x, o);
  stats_kernel<<<C, 256, 0, stream>>>(o, stats);
  bn_kernel<<<(BB * C * NN / 4) / 256, 256, 0, stream>>>(o, stats, bng, bnb, (float*)d_out);
}